// Round 7
// baseline (244.961 us; speedup 1.0000x reference)
//
#include <hip/hip_runtime.h>
#include <cstdint>
#include <cstddef>

typedef unsigned short ushort_t;
typedef unsigned int u32;
typedef __attribute__((ext_vector_type(8))) short bf16x8;
typedef __attribute__((ext_vector_type(4))) float f32x4;
typedef __attribute__((ext_vector_type(4))) unsigned short u16x4;

#define DEV static __device__ __forceinline__

DEV ushort_t f2bf(float f) {
  u32 x = __float_as_uint(f);
  x += 0x7fff + ((x >> 16) & 1);
  return (ushort_t)(x >> 16);
}
DEV float bf2f(ushort_t u) { return __uint_as_float(((u32)u) << 16); }

DEV void gload16(const ushort_t* g, ushort_t* l) {
  __builtin_amdgcn_global_load_lds(
      (const __attribute__((address_space(1))) void*)g,
      (__attribute__((address_space(3))) void*)l, 16, 0, 0);
}

// Dims: B=8, S=512, D=1024, H=16, DH=64, M=B*S=4096 per side.

// ---------------------------------------------------------------------------
__global__ __launch_bounds__(256) void cvt_inputs(
    const float* __restrict__ xa, const float* __restrict__ xb,
    ushort_t* __restrict__ oa, ushort_t* __restrict__ ob) {
  int i = blockIdx.x * 256 + threadIdx.x;
  f32x4 va = ((const f32x4*)xa)[i];
  f32x4 vb = ((const f32x4*)xb)[i];
  u16x4 ua, ub;
#pragma unroll
  for (int j = 0; j < 4; ++j) { ua[j] = f2bf(va[j]); ub[j] = f2bf(vb[j]); }
  ((u16x4*)oa)[i] = ua;
  ((u16x4*)ob)[i] = ub;
}

// ---------------------------------------------------------------------------
// z<8: W [K=1024][1024] f32 -> Wt [1024][1024] bf16 into WTall slot z.
// z==8: gate W [2048][1024] -> WgT [1024][2048].
// z==9,10: plain f32->bf16 of Wo into WoBF slot z-9.
struct Src11 { const float* p[11]; };

__global__ __launch_bounds__(256) void transpose_cvt(
    Src11 srcs, ushort_t* __restrict__ WTall, ushort_t* __restrict__ WgT,
    ushort_t* __restrict__ WoBF) {
  const int z = blockIdx.z;
  if (z != 8 && blockIdx.y >= 32) return;
  const float* src = srcs.p[z];
  int tx = threadIdx.x & 31, ty = threadIdx.x >> 5;
  int n0 = blockIdx.x << 5, k0 = blockIdx.y << 5;
  if (z >= 9) {
    ushort_t* dst = WoBF + ((size_t)(z - 9) << 20);
#pragma unroll
    for (int i = 0; i < 4; ++i) {
      size_t off = (size_t)(k0 + ty + i * 8) * 1024 + n0 + tx;
      dst[off] = f2bf(src[off]);
    }
    return;
  }
  const int K = (z == 8) ? 2048 : 1024;
  ushort_t* dst = (z == 8) ? WgT : WTall + ((size_t)z << 20);
  __shared__ float t[32][33];
#pragma unroll
  for (int i = 0; i < 4; ++i)
    t[ty + i * 8][tx] = src[(size_t)(k0 + ty + i * 8) * 1024 + n0 + tx];
  __syncthreads();
#pragma unroll
  for (int i = 0; i < 4; ++i)
    dst[(size_t)(n0 + ty + i * 8) * K + k0 + tx] = f2bf(t[tx][ty + i * 8]);
}

// ---------------------------------------------------------------------------
// gb2[dir][n] = sum_k bo_dir[k] * Wg[1024+k][n]  (= bo @ Wg_bot).
__global__ __launch_bounds__(256) void gb2_kernel(
    const float* __restrict__ bo0, const float* __restrict__ bo1,
    const ushort_t* __restrict__ WgT, float* __restrict__ gb2) {
  const int wgl = blockIdx.x * 4 + (threadIdx.x >> 6);  // 0..2047
  const int lane = threadIdx.x & 63;
  const int dir = wgl >> 10, n = wgl & 1023;
  const float* bo = dir ? bo1 : bo0;
  const ushort_t* wrow = WgT + ((size_t)n << 11) + 1024 + (lane << 4);
  float s = 0.f;
#pragma unroll
  for (int j = 0; j < 16; ++j) s += bo[(lane << 4) + j] * bf2f(wrow[j]);
#pragma unroll
  for (int d = 1; d < 64; d <<= 1) s += __shfl_xor(s, d, 64);
  if (lane == 0) gb2[wgl] = s;
}

// ---------------------------------------------------------------------------
// WpT[g][n][j] = sum_k Wo_g[j][k] * Wg[1024+k][n]   (= (Wo_g @ Wg_bot)^T)
__global__ __launch_bounds__(256, 3) void gemm_wp(
    const ushort_t* __restrict__ WgT, const ushort_t* __restrict__ WoBF,
    ushort_t* __restrict__ WpT) {
  __shared__ ushort_t As[128 * 64];
  __shared__ ushort_t Bs[128 * 64];
  const int tid = threadIdx.x;
  const int w = tid >> 6, lane = tid & 63;
  const int g = lane >> 4, c = lane & 15;
  const int wm = (w >> 1) << 6, wn = (w & 1) << 6;
  const int m0 = blockIdx.x << 7, n0 = blockIdx.y << 7;
  const int group = m0 >> 10;
  const int csw = (lane & 7) ^ (lane >> 3);

  f32x4 acc[4][4];
#pragma unroll
  for (int i = 0; i < 4; ++i)
#pragma unroll
    for (int j = 0; j < 4; ++j) acc[i][j] = f32x4{0.f, 0.f, 0.f, 0.f};

  for (int k0 = 0; k0 < 1024; k0 += 64) {
#pragma unroll
    for (int i = 0; i < 4; ++i) {
      const int chunk = (w << 2) + i;
      const int row = (chunk << 3) + (lane >> 3);
      gload16(WgT + ((size_t)((m0 + row) & 1023) << 11) + 1024 + k0 + (csw << 3),
              &As[(size_t)chunk << 9]);
      gload16(WoBF + ((size_t)group << 20) + ((size_t)(n0 + row) << 10) + k0 + (csw << 3),
              &Bs[(size_t)chunk << 9]);
    }
    __syncthreads();
    const int cg = c & 7;
#pragma unroll
    for (int ks = 0; ks < 2; ++ks) {
      bf16x8 af[4], bfr[4];
#pragma unroll
      for (int mi = 0; mi < 4; ++mi)
        af[mi] = *(const bf16x8*)&As[((wm + mi * 16 + c) << 6) +
                                     ((((ks << 2) | g) ^ cg) << 3)];
#pragma unroll
      for (int ni = 0; ni < 4; ++ni)
        bfr[ni] = *(const bf16x8*)&Bs[((wn + ni * 16 + c) << 6) +
                                      ((((ks << 2) | g) ^ cg) << 3)];
#pragma unroll
      for (int mi = 0; mi < 4; ++mi)
#pragma unroll
        for (int ni = 0; ni < 4; ++ni)
          acc[mi][ni] = __builtin_amdgcn_mfma_f32_16x16x32_bf16(
              af[mi], bfr[ni], acc[mi][ni], 0, 0, 0);
    }
    __syncthreads();
  }
#pragma unroll
  for (int ni = 0; ni < 4; ++ni) {
    const int n = n0 + wn + ni * 16 + c;
#pragma unroll
    for (int mi = 0; mi < 4; ++mi) {
      const int mb = m0 + wm + mi * 16 + (g << 2);
      f32x4 a = acc[mi][ni];
#pragma unroll
      for (int r = 0; r < 4; ++r)
        WpT[((size_t)group << 20) + ((size_t)((mb + r) & 1023) << 10) + n] = f2bf(a[r]);
    }
  }
}

// ---------------------------------------------------------------------------
// 128x128 / BK=32 / 4-wave GEMM with one-tile-lookahead LDS double buffer
// (T3-minimum 2-phase: issue next-tile stage BEFORE compute, single barrier
// per tile). LDS 32 KB total -> 3 blocks/CU. Linear LDS dest + inverse-XOR
// source + XOR read (2-way max per 16-lane quarter).
// Q/K output slots are GEMM-natural [4096][1024]; V slots stay [b][h][d][s].
enum { M_QKVG = 0, M_OG = 1 };
struct Bias8 { const float* p[8]; };

template <int MODE>
__global__ __launch_bounds__(256, 3) void gemm_kernel(
    const ushort_t* __restrict__ Aa, const ushort_t* __restrict__ Ab,
    const ushort_t* __restrict__ WTall, const ushort_t* __restrict__ WgT,
    const ushort_t* __restrict__ WpT, Bias8 bt, const float* __restrict__ gb2,
    ushort_t* __restrict__ outQ, ushort_t* __restrict__ gt) {
  __shared__ ushort_t As[2][128 * 32];
  __shared__ ushort_t Bs[2][128 * 32];
  const int tid = threadIdx.x;
  const int w = tid >> 6, lane = tid & 63;
  const int g = lane >> 4, c = lane & 15;
  const int wm = (w >> 1) << 6, wn = (w & 1) << 6;
  const int bid = (int)blockIdx.x;
  const int xcd = bid & 7, idx = bid >> 3;
  const int mt = (xcd << 3) + (idx & 7), nt = idx >> 3;
  const int m0 = mt << 7, n0 = nt << 7;
  const int group = m0 >> 12;
  const int nch = n0 >> 10;

  const ushort_t* Asrc = (MODE == M_QKVG)
      ? ((group ? Ab : Aa) + ((size_t)(m0 & 4095) << 10))
      : (Aa + ((size_t)m0 << 10));

  const ushort_t* Bb;
  int bstr, bidx = -1;
  if (MODE == M_QKVG) {
    if (nch < 3) {
      bidx = group * 3 + nch;
      Bb = WTall + ((size_t)bidx << 20) + ((size_t)(n0 & 1023) << 10);
      bstr = 1024;
    } else {
      Bb = WgT + ((size_t)(n0 & 1023) << 11);
      bstr = 2048;
    }
  } else {
    if (nch == 0) {
      Bb = WTall + ((size_t)(6 + group) << 20) + ((size_t)n0 << 10);
      bstr = 1024;
    } else {
      Bb = WpT + ((size_t)group << 20) + ((size_t)(n0 & 1023) << 10);
      bstr = 1024;
    }
  }

  // Stage one BK=32 tile (8 KB per operand): 2 wave-instructions per operand,
  // each 64 lanes x 16B contiguous LDS (wave-uniform dest, per-lane source).
  auto stage = [&](int bf_, int k0) {
#pragma unroll
    for (int j = 0; j < 2; ++j) {
      const int blkc = (w << 1) + j;                 // 0..7 (1 KB block)
      const int row = (blkc << 4) + (lane >> 2);     // 0..127
      const int cs = (lane & 3) ^ ((row >> 1) & 3);  // inverse-swizzled source
      gload16(Asrc + ((size_t)row << 10) + k0 + (cs << 3), &As[bf_][blkc << 9]);
      gload16(Bb + (size_t)row * bstr + k0 + (cs << 3), &Bs[bf_][blkc << 9]);
    }
  };

  f32x4 acc[4][4];
#pragma unroll
  for (int i = 0; i < 4; ++i)
#pragma unroll
    for (int j = 0; j < 4; ++j) acc[i][j] = f32x4{0.f, 0.f, 0.f, 0.f};

  stage(0, 0);
  __syncthreads();
#pragma unroll 2
  for (int t = 0; t < 32; ++t) {
    const int buf = t & 1;
    if (t < 31) stage(buf ^ 1, (t + 1) << 5);  // prefetch flies under compute
    bf16x8 af[4], bfr[4];
#pragma unroll
    for (int mi = 0; mi < 4; ++mi) {
      const int row = wm + mi * 16 + c;
      af[mi] = *(const bf16x8*)&As[buf][(row << 5) + ((g ^ ((row >> 1) & 3)) << 3)];
    }
#pragma unroll
    for (int ni = 0; ni < 4; ++ni) {
      const int row = wn + ni * 16 + c;
      bfr[ni] = *(const bf16x8*)&Bs[buf][(row << 5) + ((g ^ ((row >> 1) & 3)) << 3)];
    }
    __builtin_amdgcn_s_setprio(1);
#pragma unroll
    for (int mi = 0; mi < 4; ++mi)
#pragma unroll
      for (int ni = 0; ni < 4; ++ni)
        acc[mi][ni] = __builtin_amdgcn_mfma_f32_16x16x32_bf16(
            af[mi], bfr[ni], acc[mi][ni], 0, 0, 0);
    __builtin_amdgcn_s_setprio(0);
    __syncthreads();  // drains vmcnt (next tile staged) + lgkm (reads done)
  }

  // Epilogue. D frag: row(M) = 4*(lane>>4)+reg, col(N) = lane&15.
#pragma unroll
  for (int ni = 0; ni < 4; ++ni) {
    const int n = n0 + wn + ni * 16 + c;
    const int nloc = n & 1023;
    float bv;
    if (MODE == M_QKVG)
      bv = (nch < 3) ? bt.p[bidx][nloc]
                     : bt.p[6][nloc] + gb2[(group << 10) + nloc];
    else
      bv = (nch == 0) ? bt.p[group][nloc] : 0.f;
#pragma unroll
    for (int mi = 0; mi < 4; ++mi) {
      const int mb = m0 + wm + mi * 16 + (g << 2);
      f32x4 a = acc[mi][ni];
      if (MODE == M_QKVG) {
        if (nch < 3) {
          const int mrow = mb & 4095;
          ushort_t* base = outQ + ((size_t)bidx << 22);
          if (bidx == 1 || bidx == 5) {  // V^T [b][h][d][s] (needed by PV)
            const int b = mrow >> 9, s = mrow & 511;
            const int h = nloc >> 6, d = nloc & 63;
            u16x4 o;
#pragma unroll
            for (int r = 0; r < 4; ++r) o[r] = f2bf(a[r] + bv);
            *(u16x4*)&base[(((size_t)((b * 16 + h) * 64 + d)) << 9) + s] = o;
          } else {  // Q/K natural [m][n] rows
#pragma unroll
            for (int r = 0; r < 4; ++r)
              base[((size_t)(mrow + r) << 10) + nloc] = f2bf(a[r] + bv);
          }
        } else {  // gt = X @ Wg_top + gate_b + gb2
#pragma unroll
          for (int r = 0; r < 4; ++r)
            gt[((size_t)(mb + r) << 10) + nloc] = f2bf(a[r] + bv);
        }
      } else {
        if (nch == 0) {  // ao = ctx @ Wo + bo
#pragma unroll
          for (int r = 0; r < 4; ++r)
            outQ[((size_t)(mb + r) << 10) + nloc] = f2bf(a[r] + bv);
        } else {  // gpart = ctx @ W'
#pragma unroll
          for (int r = 0; r < 4; ++r)
            gt[((size_t)(mb + r) << 10) + nloc] = f2bf(a[r]);
        }
      }
    }
  }
}

// ---------------------------------------------------------------------------
// Flash-style fused attention, both dirs. Q/K slots are [4096][1024] natural
// rows (row = b*512+s, col = h*64+d); V slots are [b][h][d][s].
// KL row-shift dropped (softmax shift-invariant). scores^T = mfma(K,Q).
__global__ __launch_bounds__(256, 4) void attn_kernel(
    const ushort_t* __restrict__ QKV, ushort_t* __restrict__ ctx) {
  __shared__ ushort_t Ks[2][4096];
  __shared__ ushort_t Vs[2][4096];
  const int tid = threadIdx.x, w = tid >> 6, lane = tid & 63;
  const int g = lane >> 4, c = lane & 15, c7 = c & 7;
  const int bid = (int)blockIdx.x;
  const int wid = (bid & 7) * 256 + (bid >> 3);  // XCD-contiguous work ids
  const int dir = wid >> 10;
  const int bh = (wid >> 3) & 127, qt = wid & 7;
  const int b = bh >> 4, h = bh & 15;
  const int q0 = (qt << 6) + (w << 4);
  const int qs = dir ? 2 : 3, ks = dir ? 4 : 0, vs = dir ? 5 : 1;
  const ushort_t* Qb = QKV + ((size_t)qs << 22) + (((size_t)b << 9) << 10) + (h << 6);
  const ushort_t* Kb = QKV + ((size_t)ks << 22) + (((size_t)b << 9) << 10) + (h << 6);
  const ushort_t* Vb = QKV + ((size_t)vs << 22) + ((size_t)bh << 15);  // [64][512]

  // K chunk cc: rows cc*64..+63 (k), 64 d-cols at row stride 1024. 8 KB.
  auto stageK = [&](int bb, int kc) {
#pragma unroll
    for (int i = 0; i < 2; ++i) {
      int idx = tid + (i << 8);
      int r = idx >> 3, sl = idx & 7;
      int cs = sl ^ (r & 7);
      gload16(Kb + ((size_t)((kc << 6) + r) << 10) + (cs << 3), &Ks[bb][idx << 3]);
    }
  };
  // V chunk cc: 64 d-rows, s-cols cc*64..+63 from V^T [64][512]. 8 KB.
  auto stageV = [&](int bb, int vc) {
#pragma unroll
    for (int i = 0; i < 2; ++i) {
      int idx = tid + (i << 8);
      int r = idx >> 3, sl = idx & 7;
      int cs = sl ^ (r & 7);
      gload16(Vb + ((size_t)r << 9) + (vc << 6) + (cs << 3), &Vs[bb][idx << 3]);
    }
  };

  bf16x8 qf0 = *(const bf16x8*)&Qb[((size_t)(q0 + c) << 10) + (g << 3)];
  bf16x8 qf1 = *(const bf16x8*)&Qb[((size_t)(q0 + c) << 10) + 32 + (g << 3)];

  const float SC = 0.125f;  // 1/sqrt(64)
  float m = -1e30f, sum = 0.f;
  f32x4 pacc[4];
#pragma unroll
  for (int dt = 0; dt < 4; ++dt) pacc[dt] = f32x4{0.f, 0.f, 0.f, 0.f};
  const int s1 = ((g & 1) << 5) + c;  // repack source lanes
  const int s2 = s1 + 16;
  const bool hi = (g >> 1) != 0;

  stageK(0, 0);
  stageV(0, 0);
  __syncthreads();

#pragma unroll
  for (int cc = 0; cc < 8; ++cc) {
    const int buf = cc & 1;
    if (cc < 7) { stageK(buf ^ 1, cc + 1); stageV(buf ^ 1, cc + 1); }

    // QK^T for this chunk: 4 tiles of 16 k-rows. st[t] rows = 16t+4g+reg.
    f32x4 st[4];
    __builtin_amdgcn_s_setprio(1);
#pragma unroll
    for (int t = 0; t < 4; ++t) {
      const ushort_t* base = &Ks[buf][((t << 4) + c) << 6];
      bf16x8 a0 = *(const bf16x8*)&base[(g ^ c7) << 3];
      bf16x8 a1 = *(const bf16x8*)&base[((4 | g) ^ c7) << 3];
      f32x4 z = {0.f, 0.f, 0.f, 0.f};
      z = __builtin_amdgcn_mfma_f32_16x16x32_bf16(a0, qf0, z, 0, 0, 0);
      z = __builtin_amdgcn_mfma_f32_16x16x32_bf16(a1, qf1, z, 0, 0, 0);
      st[t] = z;
    }
    __builtin_amdgcn_s_setprio(0);

    // online softmax: chunk max (cross-g reduce), rescale running state
    float mx = fmaxf(fmaxf(st[0][0], st[0][1]), fmaxf(st[0][2], st[0][3]));
#pragma unroll
    for (int t = 1; t < 4; ++t)
      mx = fmaxf(mx, fmaxf(fmaxf(st[t][0], st[t][1]), fmaxf(st[t][2], st[t][3])));
    mx = fmaxf(mx, __shfl_xor(mx, 16, 64));
    mx = fmaxf(mx, __shfl_xor(mx, 32, 64));
    const float mn = fmaxf(m, mx);
    const float scale = __expf((m - mn) * SC);
    m = mn;
    float ls = 0.f;
#pragma unroll
    for (int t = 0; t < 4; ++t)
#pragma unroll
      for (int r = 0; r < 4; ++r) {
        float p = __expf((st[t][r] - mn) * SC);
        st[t][r] = p;
        ls += p;
      }
    ls += __shfl_xor(ls, 16, 64);
    ls += __shfl_xor(ls, 32, 64);
    sum = sum * scale + ls;
#pragma unroll
    for (int dt = 0; dt < 4; ++dt)
#pragma unroll
      for (int r = 0; r < 4; ++r) pacc[dt][r] *= scale;

    // PV for this chunk: 2 k-units of 32, repack P via shuffles, 8 MFMA
#pragma unroll
    for (int u = 0; u < 2; ++u) {
      u32 A0 = ((u32)f2bf(st[2 * u][1]) << 16) | f2bf(st[2 * u][0]);
      u32 A1p = ((u32)f2bf(st[2 * u][3]) << 16) | f2bf(st[2 * u][2]);
      u32 B0 = ((u32)f2bf(st[2 * u + 1][1]) << 16) | f2bf(st[2 * u + 1][0]);
      u32 B1 = ((u32)f2bf(st[2 * u + 1][3]) << 16) | f2bf(st[2 * u + 1][2]);
      u32 xA0 = (u32)__shfl((int)A0, s1, 64), xA1 = (u32)__shfl((int)A1p, s1, 64);
      u32 xB0 = (u32)__shfl((int)B0, s1, 64), xB1 = (u32)__shfl((int)B1, s1, 64);
      u32 yA0 = (u32)__shfl((int)A0, s2, 64), yA1 = (u32)__shfl((int)A1p, s2, 64);
      u32 yB0 = (u32)__shfl((int)B0, s2, 64), yB1 = (u32)__shfl((int)B1, s2, 64);
      union { bf16x8 v; u32 wd[4]; } pb;
      pb.wd[0] = hi ? xB0 : xA0;
      pb.wd[1] = hi ? xB1 : xA1;
      pb.wd[2] = hi ? yB0 : yA0;
      pb.wd[3] = hi ? yB1 : yA1;
      __builtin_amdgcn_s_setprio(1);
#pragma unroll
      for (int dt = 0; dt < 4; ++dt) {
        bf16x8 av = *(const bf16x8*)
            &Vs[buf][(((dt << 4) + c) << 6) + ((((u << 2) | g) ^ c7) << 3)];
        pacc[dt] = __builtin_amdgcn_mfma_f32_16x16x32_bf16(av, pb.v, pacc[dt], 0, 0, 0);
      }
      __builtin_amdgcn_s_setprio(0);
    }
    __syncthreads();
  }

  const float inv = 1.0f / sum;
  size_t obase = ((size_t)dir << 22) + ((size_t)(b * 512 + q0 + c) << 10) + (h << 6);
#pragma unroll
  for (int dt = 0; dt < 4; ++dt) {
    u16x4 o;
#pragma unroll
    for (int r = 0; r < 4; ++r) o[r] = f2bf(pacc[dt][r] * inv);
    *(u16x4*)&ctx[obase + (dt << 4) + (g << 2)] = o;
  }
}

// ---------------------------------------------------------------------------
// gate = sigmoid(gt + gpart); f = gate*x + (1-gate)*ao; out = LayerNorm(f)
__global__ __launch_bounds__(256) void fuse_ln(
    const float* __restrict__ xt, const float* __restrict__ xc,
    const ushort_t* __restrict__ ao, const ushort_t* __restrict__ gt,
    const ushort_t* __restrict__ gp,
    const float* __restrict__ lng, const float* __restrict__ lnb,
    float* __restrict__ out) {
  const int row = blockIdx.x, dir = row >> 12, r = row & 4095;
  const float* x = (dir ? xc : xt) + ((size_t)r << 10);
  const ushort_t* a = ao + ((size_t)row << 10);
  const ushort_t* g1 = gt + ((size_t)row << 10);
  const ushort_t* g2 = gp + ((size_t)row << 10);
  float* o = out + ((size_t)row << 10);
  const int t = threadIdx.x, w = t >> 6, lane = t & 63;
  f32x4 xv = ((const f32x4*)x)[t];
  u16x4 av = ((const u16x4*)a)[t];
  u16x4 gv = ((const u16x4*)g1)[t];
  u16x4 pv = ((const u16x4*)g2)[t];
  f32x4 f;
  float sm = 0.f, sq = 0.f;
#pragma unroll
  for (int j = 0; j < 4; ++j) {
    float gate = 1.f / (1.f + __expf(-(bf2f(gv[j]) + bf2f(pv[j]))));
    float fv = gate * xv[j] + (1.f - gate) * bf2f(av[j]);
    f[j] = fv; sm += fv; sq += fv * fv;
  }
#pragma unroll
  for (int d = 1; d < 64; d <<= 1) {
    sm += __shfl_xor(sm, d, 64);
    sq += __shfl_xor(sq, d, 64);
  }
  __shared__ float ps[8];
  if (lane == 0) { ps[w] = sm; ps[4 + w] = sq; }
  __syncthreads();
  sm = ps[0] + ps[1] + ps[2] + ps[3];
  sq = ps[4] + ps[5] + ps[6] + ps[7];
  const float mu = sm * (1.f / 1024.f);
  const float var = sq * (1.f / 1024.f) - mu * mu;
  const float rstd = rsqrtf(var + 1e-5f);
  f32x4 lg = ((const f32x4*)lng)[t], lb = ((const f32x4*)lnb)[t];
  f32x4 ov;
#pragma unroll
  for (int j = 0; j < 4; ++j) ov[j] = lg[j] * (f[j] - mu) * rstd + lb[j];
  ((f32x4*)o)[t] = ov;
}

// ---------------------------------------------------------------------------
extern "C" void kernel_launch(void* const* d_in, const int* in_sizes, int n_in,
                              void* d_out, int out_size, void* d_ws, size_t ws_size,
                              hipStream_t stream) {
  (void)in_sizes; (void)n_in; (void)out_size; (void)ws_size;
  const float* title = (const float*)d_in[0];
  const float* content = (const float*)d_in[1];

  char* ws = (char*)d_ws;
  const size_t MB = 1u << 20;
  ushort_t* Xt    = (ushort_t*)(ws + 0 * MB);    // 8 MB bf16 [4096][1024]
  ushort_t* Xc    = (ushort_t*)(ws + 8 * MB);    // 8 MB
  ushort_t* ctx   = (ushort_t*)(ws + 0 * MB);    // 16 MB (X dead after QKVG)
  ushort_t* WTall = (ushort_t*)(ws + 16 * MB);   // 16 MB: 8 slots [1024][1024]
  ushort_t* WgT   = (ushort_t*)(ws + 32 * MB);   // 4 MB [1024][2048]
  ushort_t* QKV   = (ushort_t*)(ws + 36 * MB);   // 48 MB: 6 slots of 8 MB
  ushort_t* ao    = (ushort_t*)(ws + 36 * MB);   // 16 MB (QKV slots 0-1, dead post-attn)
  ushort_t* gpart = (ushort_t*)(ws + 52 * MB);   // 16 MB (QKV slots 2-3, dead post-attn)
  ushort_t* gt    = (ushort_t*)(ws + 84 * MB);   // 16 MB bf16 [8192][1024]
  ushort_t* WoBF  = (ushort_t*)(ws + 100 * MB);  // 4 MB: 2 slots [1024][1024]
  ushort_t* WpT   = (ushort_t*)(ws + 104 * MB);  // 4 MB: 2 slots [1024][1024]
  float*    gb2   = (float*)   (ws + 108 * MB);  // 8 KB [2][1024]

  cvt_inputs<<<4096, 256, 0, stream>>>(title, content, Xt, Xc);

  // slots: {t2c_wk,t2c_wv,c2t_wq, t2c_wq,c2t_wk,c2t_wv, t2c_wo,c2t_wo}, gate, Wo x2
  Src11 srcs;
  srcs.p[0] = (const float*)d_in[4];  srcs.p[1] = (const float*)d_in[6];
  srcs.p[2] = (const float*)d_in[10]; srcs.p[3] = (const float*)d_in[2];
  srcs.p[4] = (const float*)d_in[12]; srcs.p[5] = (const float*)d_in[14];
  srcs.p[6] = (const float*)d_in[8];  srcs.p[7] = (const float*)d_in[16];
  srcs.p[8] = (const float*)d_in[18];
  srcs.p[9] = (const float*)d_in[8];  srcs.p[10] = (const float*)d_in[16];
  transpose_cvt<<<dim3(32, 64, 11), 256, 0, stream>>>(srcs, WTall, WgT, WoBF);

  gb2_kernel<<<512, 256, 0, stream>>>((const float*)d_in[9], (const float*)d_in[17],
                                      WgT, gb2);
  gemm_wp<<<dim3(16, 8), 256, 0, stream>>>(WgT, WoBF, WpT);

  Bias8 bq;
  bq.p[0] = (const float*)d_in[5];  bq.p[1] = (const float*)d_in[7];
  bq.p[2] = (const float*)d_in[11]; bq.p[3] = (const float*)d_in[3];
  bq.p[4] = (const float*)d_in[13]; bq.p[5] = (const float*)d_in[15];
  bq.p[6] = (const float*)d_in[19]; bq.p[7] = nullptr;
  gemm_kernel<M_QKVG><<<2048, 256, 0, stream>>>(Xt, Xc, WTall, WgT, WpT, bq, gb2,
                                                QKV, gt);

  attn_kernel<<<2048, 256, 0, stream>>>(QKV, ctx);

  Bias8 bo;
  bo.p[0] = (const float*)d_in[9]; bo.p[1] = (const float*)d_in[17];
  for (int i = 2; i < 8; ++i) bo.p[i] = nullptr;
  gemm_kernel<M_OG><<<1024, 256, 0, stream>>>(ctx, nullptr, WTall, WgT, WpT, bo, gb2,
                                              ao, gpart);

  fuse_ln<<<8192, 256, 0, stream>>>(title, content, ao, gt, gpart,
                                    (const float*)d_in[20], (const float*)d_in[21],
                                    (float*)d_out);
}

// Round 8
// 225.427 us; speedup vs baseline: 1.0867x; 1.0867x over previous
//
#include <hip/hip_runtime.h>
#include <cstdint>
#include <cstddef>

typedef unsigned short ushort_t;
typedef unsigned int u32;
typedef __attribute__((ext_vector_type(8))) short bf16x8;
typedef __attribute__((ext_vector_type(4))) float f32x4;
typedef __attribute__((ext_vector_type(4))) unsigned short u16x4;

#define DEV static __device__ __forceinline__

DEV ushort_t f2bf(float f) {
  u32 x = __float_as_uint(f);
  x += 0x7fff + ((x >> 16) & 1);
  return (ushort_t)(x >> 16);
}
DEV float bf2f(ushort_t u) { return __uint_as_float(((u32)u) << 16); }

DEV void gload16(const ushort_t* g, ushort_t* l) {
  __builtin_amdgcn_global_load_lds(
      (const __attribute__((address_space(1))) void*)g,
      (__attribute__((address_space(3))) void*)l, 16, 0, 0);
}

// Dims: B=8, S=512, D=1024, H=16, DH=64, M=B*S=4096 per side.

// ---------------------------------------------------------------------------
__global__ __launch_bounds__(256) void cvt_inputs(
    const float* __restrict__ xa, const float* __restrict__ xb,
    ushort_t* __restrict__ oa, ushort_t* __restrict__ ob) {
  int i = blockIdx.x * 256 + threadIdx.x;
  f32x4 va = ((const f32x4*)xa)[i];
  f32x4 vb = ((const f32x4*)xb)[i];
  u16x4 ua, ub;
#pragma unroll
  for (int j = 0; j < 4; ++j) { ua[j] = f2bf(va[j]); ub[j] = f2bf(vb[j]); }
  ((u16x4*)oa)[i] = ua;
  ((u16x4*)ob)[i] = ub;
}

// ---------------------------------------------------------------------------
// z<8: W [K=1024][1024] f32 -> Wt [1024][1024] bf16 into WTall slot z.
// z==8: gate W [2048][1024] -> WgT [1024][2048].
// z==9,10: plain f32->bf16 of Wo into WoBF slot z-9.
struct Src11 { const float* p[11]; };

__global__ __launch_bounds__(256) void transpose_cvt(
    Src11 srcs, ushort_t* __restrict__ WTall, ushort_t* __restrict__ WgT,
    ushort_t* __restrict__ WoBF) {
  const int z = blockIdx.z;
  if (z != 8 && blockIdx.y >= 32) return;
  const float* src = srcs.p[z];
  int tx = threadIdx.x & 31, ty = threadIdx.x >> 5;
  int n0 = blockIdx.x << 5, k0 = blockIdx.y << 5;
  if (z >= 9) {
    ushort_t* dst = WoBF + ((size_t)(z - 9) << 20);
#pragma unroll
    for (int i = 0; i < 4; ++i) {
      size_t off = (size_t)(k0 + ty + i * 8) * 1024 + n0 + tx;
      dst[off] = f2bf(src[off]);
    }
    return;
  }
  const int K = (z == 8) ? 2048 : 1024;
  ushort_t* dst = (z == 8) ? WgT : WTall + ((size_t)z << 20);
  __shared__ float t[32][33];
#pragma unroll
  for (int i = 0; i < 4; ++i)
    t[ty + i * 8][tx] = src[(size_t)(k0 + ty + i * 8) * 1024 + n0 + tx];
  __syncthreads();
#pragma unroll
  for (int i = 0; i < 4; ++i)
    dst[(size_t)(n0 + ty + i * 8) * K + k0 + tx] = f2bf(t[tx][ty + i * 8]);
}

// ---------------------------------------------------------------------------
// gb2[dir][n] = sum_k bo_dir[k] * Wg[1024+k][n]  (= bo @ Wg_bot).
__global__ __launch_bounds__(256) void gb2_kernel(
    const float* __restrict__ bo0, const float* __restrict__ bo1,
    const ushort_t* __restrict__ WgT, float* __restrict__ gb2) {
  const int wgl = blockIdx.x * 4 + (threadIdx.x >> 6);  // 0..2047
  const int lane = threadIdx.x & 63;
  const int dir = wgl >> 10, n = wgl & 1023;
  const float* bo = dir ? bo1 : bo0;
  const ushort_t* wrow = WgT + ((size_t)n << 11) + 1024 + (lane << 4);
  float s = 0.f;
#pragma unroll
  for (int j = 0; j < 16; ++j) s += bo[(lane << 4) + j] * bf2f(wrow[j]);
#pragma unroll
  for (int d = 1; d < 64; d <<= 1) s += __shfl_xor(s, d, 64);
  if (lane == 0) gb2[wgl] = s;
}

// ---------------------------------------------------------------------------
// WpT[g][n][j] = sum_k Wo_g[j][k] * Wg[1024+k][n]   (= (Wo_g @ Wg_bot)^T)
__global__ __launch_bounds__(256, 3) void gemm_wp(
    const ushort_t* __restrict__ WgT, const ushort_t* __restrict__ WoBF,
    ushort_t* __restrict__ WpT) {
  __shared__ ushort_t As[128 * 64];
  __shared__ ushort_t Bs[128 * 64];
  const int tid = threadIdx.x;
  const int w = tid >> 6, lane = tid & 63;
  const int g = lane >> 4, c = lane & 15;
  const int wm = (w >> 1) << 6, wn = (w & 1) << 6;
  const int m0 = blockIdx.x << 7, n0 = blockIdx.y << 7;
  const int group = m0 >> 10;
  const int csw = (lane & 7) ^ (lane >> 3);

  f32x4 acc[4][4];
#pragma unroll
  for (int i = 0; i < 4; ++i)
#pragma unroll
    for (int j = 0; j < 4; ++j) acc[i][j] = f32x4{0.f, 0.f, 0.f, 0.f};

  for (int k0 = 0; k0 < 1024; k0 += 64) {
#pragma unroll
    for (int i = 0; i < 4; ++i) {
      const int chunk = (w << 2) + i;
      const int row = (chunk << 3) + (lane >> 3);
      gload16(WgT + ((size_t)((m0 + row) & 1023) << 11) + 1024 + k0 + (csw << 3),
              &As[(size_t)chunk << 9]);
      gload16(WoBF + ((size_t)group << 20) + ((size_t)(n0 + row) << 10) + k0 + (csw << 3),
              &Bs[(size_t)chunk << 9]);
    }
    __syncthreads();
    const int cg = c & 7;
#pragma unroll
    for (int ks = 0; ks < 2; ++ks) {
      bf16x8 af[4], bfr[4];
#pragma unroll
      for (int mi = 0; mi < 4; ++mi)
        af[mi] = *(const bf16x8*)&As[((wm + mi * 16 + c) << 6) +
                                     ((((ks << 2) | g) ^ cg) << 3)];
#pragma unroll
      for (int ni = 0; ni < 4; ++ni)
        bfr[ni] = *(const bf16x8*)&Bs[((wn + ni * 16 + c) << 6) +
                                      ((((ks << 2) | g) ^ cg) << 3)];
#pragma unroll
      for (int mi = 0; mi < 4; ++mi)
#pragma unroll
        for (int ni = 0; ni < 4; ++ni)
          acc[mi][ni] = __builtin_amdgcn_mfma_f32_16x16x32_bf16(
              af[mi], bfr[ni], acc[mi][ni], 0, 0, 0);
    }
    __syncthreads();
  }
#pragma unroll
  for (int ni = 0; ni < 4; ++ni) {
    const int n = n0 + wn + ni * 16 + c;
#pragma unroll
    for (int mi = 0; mi < 4; ++mi) {
      const int mb = m0 + wm + mi * 16 + (g << 2);
      f32x4 a = acc[mi][ni];
#pragma unroll
      for (int r = 0; r < 4; ++r)
        WpT[((size_t)group << 20) + ((size_t)((mb + r) & 1023) << 10) + n] = f2bf(a[r]);
    }
  }
}

// ---------------------------------------------------------------------------
// 128x128 / BK=64 / 4-wave GEMM — the proven r5 engine (single 32KB buffer,
// 16 MFMA/barrier, 0 bank conflicts), plus an LDS-staged coalesced epilogue:
// As/Bs are dead after the K-loop and are reused as a 128x128 bf16 C-tile,
// stored with 8 rounds of fully-coalesced bf16x8 row stores.
// Q/K slots are GEMM-natural [4096][1024]; V slots stay [b][h][d][s].
enum { M_QKVG = 0, M_OG = 1 };
struct Bias8 { const float* p[8]; };

template <int MODE>
__global__ __launch_bounds__(256, 3) void gemm_kernel(
    const ushort_t* __restrict__ Aa, const ushort_t* __restrict__ Ab,
    const ushort_t* __restrict__ WTall, const ushort_t* __restrict__ WgT,
    const ushort_t* __restrict__ WpT, Bias8 bt, const float* __restrict__ gb2,
    ushort_t* __restrict__ outQ, ushort_t* __restrict__ gt) {
  __shared__ ushort_t smem[16384];  // 32 KB: As | Bs, reused as C-tile
  ushort_t* As = smem;
  ushort_t* Bs = smem + 8192;
  const int tid = threadIdx.x;
  const int w = tid >> 6, lane = tid & 63;
  const int g = lane >> 4, c = lane & 15;
  const int wm = (w >> 1) << 6, wn = (w & 1) << 6;
  const int bid = (int)blockIdx.x;
  const int xcd = bid & 7, idx = bid >> 3;
  const int mt = (xcd << 3) + (idx & 7), nt = idx >> 3;
  const int m0 = mt << 7, n0 = nt << 7;
  const int group = m0 >> 12;
  const int nch = n0 >> 10;
  const int csw = (lane & 7) ^ (lane >> 3);

  const ushort_t* Asrc = (MODE == M_QKVG)
      ? ((group ? Ab : Aa) + ((size_t)(m0 & 4095) << 10))
      : (Aa + ((size_t)m0 << 10));

  const ushort_t* Bb;
  int bstr, bidx = -1;
  if (MODE == M_QKVG) {
    if (nch < 3) {
      bidx = group * 3 + nch;
      Bb = WTall + ((size_t)bidx << 20) + ((size_t)(n0 & 1023) << 10);
      bstr = 1024;
    } else {
      Bb = WgT + ((size_t)(n0 & 1023) << 11);
      bstr = 2048;
    }
  } else {
    if (nch == 0) {
      Bb = WTall + ((size_t)(6 + group) << 20) + ((size_t)n0 << 10);
      bstr = 1024;
    } else {
      Bb = WpT + ((size_t)group << 20) + ((size_t)(n0 & 1023) << 10);
      bstr = 1024;
    }
  }

  f32x4 acc[4][4];
#pragma unroll
  for (int i = 0; i < 4; ++i)
#pragma unroll
    for (int j = 0; j < 4; ++j) acc[i][j] = f32x4{0.f, 0.f, 0.f, 0.f};

  for (int k0 = 0; k0 < 1024; k0 += 64) {
#pragma unroll
    for (int i = 0; i < 4; ++i) {
      const int chunk = (w << 2) + i;
      const int row = (chunk << 3) + (lane >> 3);
      gload16(Asrc + ((size_t)row << 10) + k0 + (csw << 3), &As[(size_t)chunk << 9]);
      gload16(Bb + (size_t)row * bstr + k0 + (csw << 3), &Bs[(size_t)chunk << 9]);
    }
    __syncthreads();
    const int cg = c & 7;
#pragma unroll
    for (int ks = 0; ks < 2; ++ks) {
      bf16x8 af[4], bfr[4];
#pragma unroll
      for (int mi = 0; mi < 4; ++mi)
        af[mi] = *(const bf16x8*)&As[((wm + mi * 16 + c) << 6) +
                                     ((((ks << 2) | g) ^ cg) << 3)];
#pragma unroll
      for (int ni = 0; ni < 4; ++ni)
        bfr[ni] = *(const bf16x8*)&Bs[((wn + ni * 16 + c) << 6) +
                                      ((((ks << 2) | g) ^ cg) << 3)];
#pragma unroll
      for (int mi = 0; mi < 4; ++mi)
#pragma unroll
        for (int ni = 0; ni < 4; ++ni)
          acc[mi][ni] = __builtin_amdgcn_mfma_f32_16x16x32_bf16(
              af[mi], bfr[ni], acc[mi][ni], 0, 0, 0);
    }
    __syncthreads();
  }

  // Epilogue. D frag: row(M) = 4*(lane>>4)+reg, col(N) = lane&15.
  const bool vt_path = (MODE == M_QKVG) && (nch < 3) && (bidx == 1 || bidx == 5);
  if (vt_path) {
    // V^T [b][h][d][s]: u16x4 along s, direct (s-contiguous per lane).
#pragma unroll
    for (int ni = 0; ni < 4; ++ni) {
      const int nloc = (n0 + wn + ni * 16 + c) & 1023;
      const float bv = bt.p[bidx][nloc];
      const int h = nloc >> 6, d = nloc & 63;
#pragma unroll
      for (int mi = 0; mi < 4; ++mi) {
        const int mrow = (m0 + wm + mi * 16 + (g << 2)) & 4095;
        const int b = mrow >> 9, s = mrow & 511;
        f32x4 a = acc[mi][ni];
        u16x4 o;
#pragma unroll
        for (int r = 0; r < 4; ++r) o[r] = f2bf(a[r] + bv);
        *(u16x4*)&outQ[((size_t)bidx << 22) +
                       (((size_t)((b * 16 + h) * 64 + d)) << 9) + s] = o;
      }
    }
  } else {
    // Stage bf16 C-tile in LDS, then 8 rounds of coalesced bf16x8 row stores.
#pragma unroll
    for (int ni = 0; ni < 4; ++ni) {
      const int col = wn + ni * 16 + c;
      const int nloc = (n0 + col) & 1023;
      float bv;
      if (MODE == M_QKVG)
        bv = (nch < 3) ? bt.p[bidx][nloc]
                       : bt.p[6][nloc] + gb2[(group << 10) + nloc];
      else
        bv = (nch == 0) ? bt.p[group][nloc] : 0.f;
#pragma unroll
      for (int mi = 0; mi < 4; ++mi) {
        const int rowb = wm + mi * 16 + (g << 2);
        f32x4 a = acc[mi][ni];
#pragma unroll
        for (int r = 0; r < 4; ++r)
          smem[((rowb + r) << 7) + col] = f2bf(a[r] + bv);
      }
    }
    __syncthreads();
    const int lr = tid >> 4;          // 0..15
    const int lc = (tid & 15) << 3;   // 0..120, step 8
    ushort_t* obase;
    size_t rbase;
    if (MODE == M_QKVG) {
      if (nch < 3) { obase = outQ + ((size_t)bidx << 22); rbase = (size_t)(m0 & 4095); }
      else         { obase = gt;                          rbase = (size_t)m0; }
    } else {
      if (nch == 0) { obase = outQ; rbase = (size_t)m0; }
      else          { obase = gt;   rbase = (size_t)m0; }
    }
    const int ncol = (n0 & 1023) + lc;
#pragma unroll
    for (int j = 0; j < 8; ++j) {
      const int row = (j << 4) + lr;
      bf16x8 v = *(const bf16x8*)&smem[(row << 7) + lc];
      *(bf16x8*)&obase[((rbase + row) << 10) + ncol] = v;
    }
  }
}

// ---------------------------------------------------------------------------
// Flash-style fused attention, both dirs. Q/K slots are [4096][1024] natural
// rows (row = b*512+s, col = h*64+d); V slots are [b][h][d][s].
// KL row-shift dropped (softmax shift-invariant). scores^T = mfma(K,Q).
__global__ __launch_bounds__(256, 4) void attn_kernel(
    const ushort_t* __restrict__ QKV, ushort_t* __restrict__ ctx) {
  __shared__ ushort_t Ks[2][4096];
  __shared__ ushort_t Vs[2][4096];
  const int tid = threadIdx.x, w = tid >> 6, lane = tid & 63;
  const int g = lane >> 4, c = lane & 15, c7 = c & 7;
  const int bid = (int)blockIdx.x;
  const int wid = (bid & 7) * 256 + (bid >> 3);  // XCD-contiguous work ids
  const int dir = wid >> 10;
  const int bh = (wid >> 3) & 127, qt = wid & 7;
  const int b = bh >> 4, h = bh & 15;
  const int q0 = (qt << 6) + (w << 4);
  const int qs = dir ? 2 : 3, ks = dir ? 4 : 0, vs = dir ? 5 : 1;
  const ushort_t* Qb = QKV + ((size_t)qs << 22) + (((size_t)b << 9) << 10) + (h << 6);
  const ushort_t* Kb = QKV + ((size_t)ks << 22) + (((size_t)b << 9) << 10) + (h << 6);
  const ushort_t* Vb = QKV + ((size_t)vs << 22) + ((size_t)bh << 15);  // [64][512]

  auto stageK = [&](int bb, int kc) {
#pragma unroll
    for (int i = 0; i < 2; ++i) {
      int idx = tid + (i << 8);
      int r = idx >> 3, sl = idx & 7;
      int cs = sl ^ (r & 7);
      gload16(Kb + ((size_t)((kc << 6) + r) << 10) + (cs << 3), &Ks[bb][idx << 3]);
    }
  };
  auto stageV = [&](int bb, int vc) {
#pragma unroll
    for (int i = 0; i < 2; ++i) {
      int idx = tid + (i << 8);
      int r = idx >> 3, sl = idx & 7;
      int cs = sl ^ (r & 7);
      gload16(Vb + ((size_t)r << 9) + (vc << 6) + (cs << 3), &Vs[bb][idx << 3]);
    }
  };

  bf16x8 qf0 = *(const bf16x8*)&Qb[((size_t)(q0 + c) << 10) + (g << 3)];
  bf16x8 qf1 = *(const bf16x8*)&Qb[((size_t)(q0 + c) << 10) + 32 + (g << 3)];

  const float SC = 0.125f;  // 1/sqrt(64)
  float m = -1e30f, sum = 0.f;
  f32x4 pacc[4];
#pragma unroll
  for (int dt = 0; dt < 4; ++dt) pacc[dt] = f32x4{0.f, 0.f, 0.f, 0.f};
  const int s1 = ((g & 1) << 5) + c;  // repack source lanes
  const int s2 = s1 + 16;
  const bool hi = (g >> 1) != 0;

  stageK(0, 0);
  stageV(0, 0);
  __syncthreads();

#pragma unroll
  for (int cc = 0; cc < 8; ++cc) {
    const int buf = cc & 1;
    if (cc < 7) { stageK(buf ^ 1, cc + 1); stageV(buf ^ 1, cc + 1); }

    f32x4 st[4];
    __builtin_amdgcn_s_setprio(1);
#pragma unroll
    for (int t = 0; t < 4; ++t) {
      const ushort_t* base = &Ks[buf][((t << 4) + c) << 6];
      bf16x8 a0 = *(const bf16x8*)&base[(g ^ c7) << 3];
      bf16x8 a1 = *(const bf16x8*)&base[((4 | g) ^ c7) << 3];
      f32x4 z = {0.f, 0.f, 0.f, 0.f};
      z = __builtin_amdgcn_mfma_f32_16x16x32_bf16(a0, qf0, z, 0, 0, 0);
      z = __builtin_amdgcn_mfma_f32_16x16x32_bf16(a1, qf1, z, 0, 0, 0);
      st[t] = z;
    }
    __builtin_amdgcn_s_setprio(0);

    float mx = fmaxf(fmaxf(st[0][0], st[0][1]), fmaxf(st[0][2], st[0][3]));
#pragma unroll
    for (int t = 1; t < 4; ++t)
      mx = fmaxf(mx, fmaxf(fmaxf(st[t][0], st[t][1]), fmaxf(st[t][2], st[t][3])));
    mx = fmaxf(mx, __shfl_xor(mx, 16, 64));
    mx = fmaxf(mx, __shfl_xor(mx, 32, 64));
    const float mn = fmaxf(m, mx);
    const float scale = __expf((m - mn) * SC);
    m = mn;
    float ls = 0.f;
#pragma unroll
    for (int t = 0; t < 4; ++t)
#pragma unroll
      for (int r = 0; r < 4; ++r) {
        float p = __expf((st[t][r] - mn) * SC);
        st[t][r] = p;
        ls += p;
      }
    ls += __shfl_xor(ls, 16, 64);
    ls += __shfl_xor(ls, 32, 64);
    sum = sum * scale + ls;
#pragma unroll
    for (int dt = 0; dt < 4; ++dt)
#pragma unroll
      for (int r = 0; r < 4; ++r) pacc[dt][r] *= scale;

#pragma unroll
    for (int u = 0; u < 2; ++u) {
      u32 A0 = ((u32)f2bf(st[2 * u][1]) << 16) | f2bf(st[2 * u][0]);
      u32 A1p = ((u32)f2bf(st[2 * u][3]) << 16) | f2bf(st[2 * u][2]);
      u32 B0 = ((u32)f2bf(st[2 * u + 1][1]) << 16) | f2bf(st[2 * u + 1][0]);
      u32 B1 = ((u32)f2bf(st[2 * u + 1][3]) << 16) | f2bf(st[2 * u + 1][2]);
      u32 xA0 = (u32)__shfl((int)A0, s1, 64), xA1 = (u32)__shfl((int)A1p, s1, 64);
      u32 xB0 = (u32)__shfl((int)B0, s1, 64), xB1 = (u32)__shfl((int)B1, s1, 64);
      u32 yA0 = (u32)__shfl((int)A0, s2, 64), yA1 = (u32)__shfl((int)A1p, s2, 64);
      u32 yB0 = (u32)__shfl((int)B0, s2, 64), yB1 = (u32)__shfl((int)B1, s2, 64);
      union { bf16x8 v; u32 wd[4]; } pb;
      pb.wd[0] = hi ? xB0 : xA0;
      pb.wd[1] = hi ? xB1 : xA1;
      pb.wd[2] = hi ? yB0 : yA0;
      pb.wd[3] = hi ? yB1 : yA1;
      __builtin_amdgcn_s_setprio(1);
#pragma unroll
      for (int dt = 0; dt < 4; ++dt) {
        bf16x8 av = *(const bf16x8*)
            &Vs[buf][(((dt << 4) + c) << 6) + ((((u << 2) | g) ^ c7) << 3)];
        pacc[dt] = __builtin_amdgcn_mfma_f32_16x16x32_bf16(av, pb.v, pacc[dt], 0, 0, 0);
      }
      __builtin_amdgcn_s_setprio(0);
    }
    __syncthreads();
  }

  const float inv = 1.0f / sum;
  size_t obase = ((size_t)dir << 22) + ((size_t)(b * 512 + q0 + c) << 10) + (h << 6);
#pragma unroll
  for (int dt = 0; dt < 4; ++dt) {
    u16x4 o;
#pragma unroll
    for (int r = 0; r < 4; ++r) o[r] = f2bf(pacc[dt][r] * inv);
    *(u16x4*)&ctx[obase + (dt << 4) + (g << 2)] = o;
  }
}

// ---------------------------------------------------------------------------
// gate = sigmoid(gt + gpart); f = gate*x + (1-gate)*ao; out = LayerNorm(f)
__global__ __launch_bounds__(256) void fuse_ln(
    const float* __restrict__ xt, const float* __restrict__ xc,
    const ushort_t* __restrict__ ao, const ushort_t* __restrict__ gt,
    const ushort_t* __restrict__ gp,
    const float* __restrict__ lng, const float* __restrict__ lnb,
    float* __restrict__ out) {
  const int row = blockIdx.x, dir = row >> 12, r = row & 4095;
  const float* x = (dir ? xc : xt) + ((size_t)r << 10);
  const ushort_t* a = ao + ((size_t)row << 10);
  const ushort_t* g1 = gt + ((size_t)row << 10);
  const ushort_t* g2 = gp + ((size_t)row << 10);
  float* o = out + ((size_t)row << 10);
  const int t = threadIdx.x, w = t >> 6, lane = t & 63;
  f32x4 xv = ((const f32x4*)x)[t];
  u16x4 av = ((const u16x4*)a)[t];
  u16x4 gv = ((const u16x4*)g1)[t];
  u16x4 pv = ((const u16x4*)g2)[t];
  f32x4 f;
  float sm = 0.f, sq = 0.f;
#pragma unroll
  for (int j = 0; j < 4; ++j) {
    float gate = 1.f / (1.f + __expf(-(bf2f(gv[j]) + bf2f(pv[j]))));
    float fv = gate * xv[j] + (1.f - gate) * bf2f(av[j]);
    f[j] = fv; sm += fv; sq += fv * fv;
  }
#pragma unroll
  for (int d = 1; d < 64; d <<= 1) {
    sm += __shfl_xor(sm, d, 64);
    sq += __shfl_xor(sq, d, 64);
  }
  __shared__ float ps[8];
  if (lane == 0) { ps[w] = sm; ps[4 + w] = sq; }
  __syncthreads();
  sm = ps[0] + ps[1] + ps[2] + ps[3];
  sq = ps[4] + ps[5] + ps[6] + ps[7];
  const float mu = sm * (1.f / 1024.f);
  const float var = sq * (1.f / 1024.f) - mu * mu;
  const float rstd = rsqrtf(var + 1e-5f);
  f32x4 lg = ((const f32x4*)lng)[t], lb = ((const f32x4*)lnb)[t];
  f32x4 ov;
#pragma unroll
  for (int j = 0; j < 4; ++j) ov[j] = lg[j] * (f[j] - mu) * rstd + lb[j];
  ((f32x4*)o)[t] = ov;
}

// ---------------------------------------------------------------------------
extern "C" void kernel_launch(void* const* d_in, const int* in_sizes, int n_in,
                              void* d_out, int out_size, void* d_ws, size_t ws_size,
                              hipStream_t stream) {
  (void)in_sizes; (void)n_in; (void)out_size; (void)ws_size;
  const float* title = (const float*)d_in[0];
  const float* content = (const float*)d_in[1];

  char* ws = (char*)d_ws;
  const size_t MB = 1u << 20;
  ushort_t* Xt    = (ushort_t*)(ws + 0 * MB);    // 8 MB bf16 [4096][1024]
  ushort_t* Xc    = (ushort_t*)(ws + 8 * MB);    // 8 MB
  ushort_t* ctx   = (ushort_t*)(ws + 0 * MB);    // 16 MB (X dead after QKVG)
  ushort_t* WTall = (ushort_t*)(ws + 16 * MB);   // 16 MB: 8 slots [1024][1024]
  ushort_t* WgT   = (ushort_t*)(ws + 32 * MB);   // 4 MB [1024][2048]
  ushort_t* QKV   = (ushort_t*)(ws + 36 * MB);   // 48 MB: 6 slots of 8 MB
  ushort_t* ao    = (ushort_t*)(ws + 36 * MB);   // 16 MB (QKV slots 0-1, dead post-attn)
  ushort_t* gpart = (ushort_t*)(ws + 52 * MB);   // 16 MB (QKV slots 2-3, dead post-attn)
  ushort_t* gt    = (ushort_t*)(ws + 84 * MB);   // 16 MB bf16 [8192][1024]
  ushort_t* WoBF  = (ushort_t*)(ws + 100 * MB);  // 4 MB: 2 slots [1024][1024]
  ushort_t* WpT   = (ushort_t*)(ws + 104 * MB);  // 4 MB: 2 slots [1024][1024]
  float*    gb2   = (float*)   (ws + 108 * MB);  // 8 KB [2][1024]

  cvt_inputs<<<4096, 256, 0, stream>>>(title, content, Xt, Xc);

  // slots: {t2c_wk,t2c_wv,c2t_wq, t2c_wq,c2t_wk,c2t_wv, t2c_wo,c2t_wo}, gate, Wo x2
  Src11 srcs;
  srcs.p[0] = (const float*)d_in[4];  srcs.p[1] = (const float*)d_in[6];
  srcs.p[2] = (const float*)d_in[10]; srcs.p[3] = (const float*)d_in[2];
  srcs.p[4] = (const float*)d_in[12]; srcs.p[5] = (const float*)d_in[14];
  srcs.p[6] = (const float*)d_in[8];  srcs.p[7] = (const float*)d_in[16];
  srcs.p[8] = (const float*)d_in[18];
  srcs.p[9] = (const float*)d_in[8];  srcs.p[10] = (const float*)d_in[16];
  transpose_cvt<<<dim3(32, 64, 11), 256, 0, stream>>>(srcs, WTall, WgT, WoBF);

  gb2_kernel<<<512, 256, 0, stream>>>((const float*)d_in[9], (const float*)d_in[17],
                                      WgT, gb2);
  gemm_wp<<<dim3(16, 8), 256, 0, stream>>>(WgT, WoBF, WpT);

  Bias8 bq;
  bq.p[0] = (const float*)d_in[5];  bq.p[1] = (const float*)d_in[7];
  bq.p[2] = (const float*)d_in[11]; bq.p[3] = (const float*)d_in[3];
  bq.p[4] = (const float*)d_in[13]; bq.p[5] = (const float*)d_in[15];
  bq.p[6] = (const float*)d_in[19]; bq.p[7] = nullptr;
  gemm_kernel<M_QKVG><<<2048, 256, 0, stream>>>(Xt, Xc, WTall, WgT, WpT, bq, gb2,
                                                QKV, gt);

  attn_kernel<<<2048, 256, 0, stream>>>(QKV, ctx);

  Bias8 bo;
  bo.p[0] = (const float*)d_in[9]; bo.p[1] = (const float*)d_in[17];
  for (int i = 2; i < 8; ++i) bo.p[i] = nullptr;
  gemm_kernel<M_OG><<<1024, 256, 0, stream>>>(ctx, nullptr, WTall, WgT, WpT, bo, gb2,
                                              ao, gpart);

  fuse_ln<<<8192, 256, 0, stream>>>(title, content, ao, gt, gpart,
                                    (const float*)d_in[20], (const float*)d_in[21],
                                    (float*)d_out);
}

// Round 9
// 220.288 us; speedup vs baseline: 1.1120x; 1.0233x over previous
//
#include <hip/hip_runtime.h>
#include <cstdint>
#include <cstddef>

typedef unsigned short ushort_t;
typedef unsigned int u32;
typedef __attribute__((ext_vector_type(8))) short bf16x8;
typedef __attribute__((ext_vector_type(4))) short bf16x4;
typedef __attribute__((ext_vector_type(4))) float f32x4;
typedef __attribute__((ext_vector_type(4))) unsigned short u16x4;

#define DEV static __device__ __forceinline__

DEV ushort_t f2bf(float f) {
  u32 x = __float_as_uint(f);
  x += 0x7fff + ((x >> 16) & 1);
  return (ushort_t)(x >> 16);
}
DEV float bf2f(ushort_t u) { return __uint_as_float(((u32)u) << 16); }

DEV u32 cvtpk(float a, float b) {  // dst.lo = bf16(a), dst.hi = bf16(b)
  u32 r;
  asm("v_cvt_pk_bf16_f32 %0, %1, %2" : "=v"(r) : "v"(a), "v"(b));
  return r;
}

DEV void gload16(const ushort_t* g, ushort_t* l) {
  __builtin_amdgcn_global_load_lds(
      (const __attribute__((address_space(1))) void*)g,
      (__attribute__((address_space(3))) void*)l, 16, 0, 0);
}

// Dims: B=8, S=512, D=1024, H=16, DH=64, M=B*S=4096 per side.

// ---------------------------------------------------------------------------
__global__ __launch_bounds__(256) void cvt_inputs(
    const float* __restrict__ xa, const float* __restrict__ xb,
    ushort_t* __restrict__ oa, ushort_t* __restrict__ ob) {
  int i = blockIdx.x * 256 + threadIdx.x;
  f32x4 va = ((const f32x4*)xa)[i];
  f32x4 vb = ((const f32x4*)xb)[i];
  u16x4 ua, ub;
#pragma unroll
  for (int j = 0; j < 4; ++j) { ua[j] = f2bf(va[j]); ub[j] = f2bf(vb[j]); }
  ((u16x4*)oa)[i] = ua;
  ((u16x4*)ob)[i] = ub;
}

// ---------------------------------------------------------------------------
// z<8: W [K=1024][1024] f32 -> Wt [1024][1024] bf16 into WTall slot z.
// z==8: gate W [2048][1024] -> WgT [1024][2048].
// z==9,10: plain f32->bf16 of Wo into WoBF slot z-9.
struct Src11 { const float* p[11]; };

__global__ __launch_bounds__(256) void transpose_cvt(
    Src11 srcs, ushort_t* __restrict__ WTall, ushort_t* __restrict__ WgT,
    ushort_t* __restrict__ WoBF) {
  const int z = blockIdx.z;
  if (z != 8 && blockIdx.y >= 32) return;
  const float* src = srcs.p[z];
  int tx = threadIdx.x & 31, ty = threadIdx.x >> 5;
  int n0 = blockIdx.x << 5, k0 = blockIdx.y << 5;
  if (z >= 9) {
    ushort_t* dst = WoBF + ((size_t)(z - 9) << 20);
#pragma unroll
    for (int i = 0; i < 4; ++i) {
      size_t off = (size_t)(k0 + ty + i * 8) * 1024 + n0 + tx;
      dst[off] = f2bf(src[off]);
    }
    return;
  }
  const int K = (z == 8) ? 2048 : 1024;
  ushort_t* dst = (z == 8) ? WgT : WTall + ((size_t)z << 20);
  __shared__ float t[32][33];
#pragma unroll
  for (int i = 0; i < 4; ++i)
    t[ty + i * 8][tx] = src[(size_t)(k0 + ty + i * 8) * 1024 + n0 + tx];
  __syncthreads();
#pragma unroll
  for (int i = 0; i < 4; ++i)
    dst[(size_t)(n0 + ty + i * 8) * K + k0 + tx] = f2bf(t[tx][ty + i * 8]);
}

// ---------------------------------------------------------------------------
// gb2[dir][n] = sum_k bo_dir[k] * Wg[1024+k][n]  (= bo @ Wg_bot).
__global__ __launch_bounds__(256) void gb2_kernel(
    const float* __restrict__ bo0, const float* __restrict__ bo1,
    const ushort_t* __restrict__ WgT, float* __restrict__ gb2) {
  const int wgl = blockIdx.x * 4 + (threadIdx.x >> 6);  // 0..2047
  const int lane = threadIdx.x & 63;
  const int dir = wgl >> 10, n = wgl & 1023;
  const float* bo = dir ? bo1 : bo0;
  const ushort_t* wrow = WgT + ((size_t)n << 11) + 1024 + (lane << 4);
  float s = 0.f;
#pragma unroll
  for (int j = 0; j < 16; ++j) s += bo[(lane << 4) + j] * bf2f(wrow[j]);
#pragma unroll
  for (int d = 1; d < 64; d <<= 1) s += __shfl_xor(s, d, 64);
  if (lane == 0) gb2[wgl] = s;
}

// ---------------------------------------------------------------------------
// WpT[g][n][j] = sum_k Wo_g[j][k] * Wg[1024+k][n]   (= (Wo_g @ Wg_bot)^T)
__global__ __launch_bounds__(256, 3) void gemm_wp(
    const ushort_t* __restrict__ WgT, const ushort_t* __restrict__ WoBF,
    ushort_t* __restrict__ WpT) {
  __shared__ ushort_t As[128 * 64];
  __shared__ ushort_t Bs[128 * 64];
  const int tid = threadIdx.x;
  const int w = tid >> 6, lane = tid & 63;
  const int g = lane >> 4, c = lane & 15;
  const int wm = (w >> 1) << 6, wn = (w & 1) << 6;
  const int m0 = blockIdx.x << 7, n0 = blockIdx.y << 7;
  const int group = m0 >> 10;
  const int csw = (lane & 7) ^ (lane >> 3);

  f32x4 acc[4][4];
#pragma unroll
  for (int i = 0; i < 4; ++i)
#pragma unroll
    for (int j = 0; j < 4; ++j) acc[i][j] = f32x4{0.f, 0.f, 0.f, 0.f};

  for (int k0 = 0; k0 < 1024; k0 += 64) {
#pragma unroll
    for (int i = 0; i < 4; ++i) {
      const int chunk = (w << 2) + i;
      const int row = (chunk << 3) + (lane >> 3);
      gload16(WgT + ((size_t)((m0 + row) & 1023) << 11) + 1024 + k0 + (csw << 3),
              &As[(size_t)chunk << 9]);
      gload16(WoBF + ((size_t)group << 20) + ((size_t)(n0 + row) << 10) + k0 + (csw << 3),
              &Bs[(size_t)chunk << 9]);
    }
    __syncthreads();
    const int cg = c & 7;
#pragma unroll
    for (int ks = 0; ks < 2; ++ks) {
      bf16x8 af[4], bfr[4];
#pragma unroll
      for (int mi = 0; mi < 4; ++mi)
        af[mi] = *(const bf16x8*)&As[((wm + mi * 16 + c) << 6) +
                                     ((((ks << 2) | g) ^ cg) << 3)];
#pragma unroll
      for (int ni = 0; ni < 4; ++ni)
        bfr[ni] = *(const bf16x8*)&Bs[((wn + ni * 16 + c) << 6) +
                                      ((((ks << 2) | g) ^ cg) << 3)];
#pragma unroll
      for (int mi = 0; mi < 4; ++mi)
#pragma unroll
        for (int ni = 0; ni < 4; ++ni)
          acc[mi][ni] = __builtin_amdgcn_mfma_f32_16x16x32_bf16(
              af[mi], bfr[ni], acc[mi][ni], 0, 0, 0);
    }
    __syncthreads();
  }
#pragma unroll
  for (int ni = 0; ni < 4; ++ni) {
    const int n = n0 + wn + ni * 16 + c;
#pragma unroll
    for (int mi = 0; mi < 4; ++mi) {
      const int mb = m0 + wm + mi * 16 + (g << 2);
      f32x4 a = acc[mi][ni];
#pragma unroll
      for (int r = 0; r < 4; ++r)
        WpT[((size_t)group << 20) + ((size_t)((mb + r) & 1023) << 10) + n] = f2bf(a[r]);
    }
  }
}

// ---------------------------------------------------------------------------
// 128x128 / BK=64 / 4-wave GEMM — proven r8 engine (single 32KB buffer,
// 16 MFMA/barrier, LDS-staged coalesced epilogue).
// ctx (OG input) is [dir][h][4096][64] (h-major); Q/K slots [4096][1024];
// V slots [b][h][d][s].
enum { M_QKVG = 0, M_OG = 1 };
struct Bias8 { const float* p[8]; };

template <int MODE>
__global__ __launch_bounds__(256, 3) void gemm_kernel(
    const ushort_t* __restrict__ Aa, const ushort_t* __restrict__ Ab,
    const ushort_t* __restrict__ WTall, const ushort_t* __restrict__ WgT,
    const ushort_t* __restrict__ WpT, Bias8 bt, const float* __restrict__ gb2,
    ushort_t* __restrict__ outQ, ushort_t* __restrict__ gt) {
  __shared__ ushort_t smem[16384];  // 32 KB: As | Bs, reused as C-tile
  ushort_t* As = smem;
  ushort_t* Bs = smem + 8192;
  const int tid = threadIdx.x;
  const int w = tid >> 6, lane = tid & 63;
  const int g = lane >> 4, c = lane & 15;
  const int wm = (w >> 1) << 6, wn = (w & 1) << 6;
  const int bid = (int)blockIdx.x;
  const int xcd = bid & 7, idx = bid >> 3;
  const int mt = (xcd << 3) + (idx & 7), nt = idx >> 3;
  const int m0 = mt << 7, n0 = nt << 7;
  const int group = m0 >> 12;
  const int nch = n0 >> 10;
  const int csw = (lane & 7) ^ (lane >> 3);

  const ushort_t* Asrc = (MODE == M_QKVG)
      ? ((group ? Ab : Aa) + ((size_t)(m0 & 4095) << 10))
      : (Aa + ((size_t)group << 22) + ((size_t)(m0 & 4095) << 6));

  const ushort_t* Bb;
  int bstr, bidx = -1;
  if (MODE == M_QKVG) {
    if (nch < 3) {
      bidx = group * 3 + nch;
      Bb = WTall + ((size_t)bidx << 20) + ((size_t)(n0 & 1023) << 10);
      bstr = 1024;
    } else {
      Bb = WgT + ((size_t)(n0 & 1023) << 11);
      bstr = 2048;
    }
  } else {
    if (nch == 0) {
      Bb = WTall + ((size_t)(6 + group) << 20) + ((size_t)n0 << 10);
      bstr = 1024;
    } else {
      Bb = WpT + ((size_t)group << 20) + ((size_t)(n0 & 1023) << 10);
      bstr = 1024;
    }
  }

  f32x4 acc[4][4];
#pragma unroll
  for (int i = 0; i < 4; ++i)
#pragma unroll
    for (int j = 0; j < 4; ++j) acc[i][j] = f32x4{0.f, 0.f, 0.f, 0.f};

  for (int k0 = 0; k0 < 1024; k0 += 64) {
#pragma unroll
    for (int i = 0; i < 4; ++i) {
      const int chunk = (w << 2) + i;
      const int row = (chunk << 3) + (lane >> 3);
      const ushort_t* ap;
      if (MODE == M_QKVG)
        ap = Asrc + ((size_t)row << 10) + k0 + (csw << 3);
      else  // ctx h-major: h = k0>>6, d = csw*8
        ap = Asrc + ((size_t)(k0 >> 6) << 18) + ((size_t)row << 6) + (csw << 3);
      gload16(ap, &As[(size_t)chunk << 9]);
      gload16(Bb + (size_t)row * bstr + k0 + (csw << 3), &Bs[(size_t)chunk << 9]);
    }
    __syncthreads();
    const int cg = c & 7;
#pragma unroll
    for (int ks = 0; ks < 2; ++ks) {
      bf16x8 af[4], bfr[4];
#pragma unroll
      for (int mi = 0; mi < 4; ++mi)
        af[mi] = *(const bf16x8*)&As[((wm + mi * 16 + c) << 6) +
                                     ((((ks << 2) | g) ^ cg) << 3)];
#pragma unroll
      for (int ni = 0; ni < 4; ++ni)
        bfr[ni] = *(const bf16x8*)&Bs[((wn + ni * 16 + c) << 6) +
                                      ((((ks << 2) | g) ^ cg) << 3)];
#pragma unroll
      for (int mi = 0; mi < 4; ++mi)
#pragma unroll
        for (int ni = 0; ni < 4; ++ni)
          acc[mi][ni] = __builtin_amdgcn_mfma_f32_16x16x32_bf16(
              af[mi], bfr[ni], acc[mi][ni], 0, 0, 0);
    }
    __syncthreads();
  }

  // Epilogue. D frag: row(M) = 4*(lane>>4)+reg, col(N) = lane&15.
  const bool vt_path = (MODE == M_QKVG) && (nch < 3) && (bidx == 1 || bidx == 5);
  if (vt_path) {
#pragma unroll
    for (int ni = 0; ni < 4; ++ni) {
      const int nloc = (n0 + wn + ni * 16 + c) & 1023;
      const float bv = bt.p[bidx][nloc];
      const int h = nloc >> 6, d = nloc & 63;
#pragma unroll
      for (int mi = 0; mi < 4; ++mi) {
        const int mrow = (m0 + wm + mi * 16 + (g << 2)) & 4095;
        const int b = mrow >> 9, s = mrow & 511;
        f32x4 a = acc[mi][ni];
        u16x4 o;
#pragma unroll
        for (int r = 0; r < 4; ++r) o[r] = f2bf(a[r] + bv);
        *(u16x4*)&outQ[((size_t)bidx << 22) +
                       (((size_t)((b * 16 + h) * 64 + d)) << 9) + s] = o;
      }
    }
  } else {
    // Stage bf16 C-tile in LDS, then 8 rounds of coalesced bf16x8 row stores.
#pragma unroll
    for (int ni = 0; ni < 4; ++ni) {
      const int col = wn + ni * 16 + c;
      const int nloc = (n0 + col) & 1023;
      float bv;
      if (MODE == M_QKVG)
        bv = (nch < 3) ? bt.p[bidx][nloc]
                       : bt.p[6][nloc] + gb2[(group << 10) + nloc];
      else
        bv = (nch == 0) ? bt.p[group][nloc] : 0.f;
#pragma unroll
      for (int mi = 0; mi < 4; ++mi) {
        const int rowb = wm + mi * 16 + (g << 2);
        f32x4 a = acc[mi][ni];
#pragma unroll
        for (int r = 0; r < 4; ++r)
          smem[((rowb + r) << 7) + col] = f2bf(a[r] + bv);
      }
    }
    __syncthreads();
    const int lr = tid >> 4;          // 0..15
    const int lc = (tid & 15) << 3;   // 0..120, step 8
    ushort_t* obase;
    size_t rbase;
    if (MODE == M_QKVG) {
      if (nch < 3) { obase = outQ + ((size_t)bidx << 22); rbase = (size_t)(m0 & 4095); }
      else         { obase = gt;                          rbase = (size_t)m0; }
    } else {
      if (nch == 0) { obase = outQ; rbase = (size_t)m0; }
      else          { obase = gt;   rbase = (size_t)m0; }
    }
    const int ncol = (n0 & 1023) + lc;
#pragma unroll
    for (int j = 0; j < 8; ++j) {
      const int row = (j << 4) + lr;
      bf16x8 v = *(const bf16x8*)&smem[(row << 7) + lc];
      *(bf16x8*)&obase[((rbase + row) << 10) + ncol] = v;
    }
  }
}

// ---------------------------------------------------------------------------
// Flash-style fused attention, both dirs. Q/K slots [4096][1024] natural; V
// slots [b][h][d][s]. KL row-shift dropped (softmax shift-invariant).
// QK^T = mfma(K,Q) 16x16x32; PV uses 16x16x16 MFMA so the P fragment IS the
// QK^T output fragment (k=4g+r, col q=c) -> zero cross-lane shuffles; P->bf16
// via v_cvt_pk_bf16_f32. ctx written h-major [dir][h][4096][64] (coalesced).
__global__ __launch_bounds__(256, 4) void attn_kernel(
    const ushort_t* __restrict__ QKV, ushort_t* __restrict__ ctx) {
  __shared__ ushort_t Ks[2][4096];
  __shared__ ushort_t Vs[2][4096];
  const int tid = threadIdx.x, w = tid >> 6, lane = tid & 63;
  const int g = lane >> 4, c = lane & 15, c7 = c & 7;
  const int bid = (int)blockIdx.x;
  const int wid = (bid & 7) * 256 + (bid >> 3);  // XCD-contiguous work ids
  const int dir = wid >> 10;
  const int bh = (wid >> 3) & 127, qt = wid & 7;
  const int b = bh >> 4, h = bh & 15;
  const int q0 = (qt << 6) + (w << 4);
  const int qs = dir ? 2 : 3, kslot = dir ? 4 : 0, vslot = dir ? 5 : 1;
  const ushort_t* Qb = QKV + ((size_t)qs << 22) + (((size_t)b << 9) << 10) + (h << 6);
  const ushort_t* Kb = QKV + ((size_t)kslot << 22) + (((size_t)b << 9) << 10) + (h << 6);
  const ushort_t* Vb = QKV + ((size_t)vslot << 22) + ((size_t)bh << 15);  // [64][512]

  auto stageK = [&](int bb, int kc) {
#pragma unroll
    for (int i = 0; i < 2; ++i) {
      int idx = tid + (i << 8);
      int r = idx >> 3, sl = idx & 7;
      int cs = sl ^ (r & 7);
      gload16(Kb + ((size_t)((kc << 6) + r) << 10) + (cs << 3), &Ks[bb][idx << 3]);
    }
  };
  auto stageV = [&](int bb, int vc) {
#pragma unroll
    for (int i = 0; i < 2; ++i) {
      int idx = tid + (i << 8);
      int r = idx >> 3, sl = idx & 7;
      int cs = sl ^ (r & 7);
      gload16(Vb + ((size_t)r << 9) + (vc << 6) + (cs << 3), &Vs[bb][idx << 3]);
    }
  };

  bf16x8 qf0 = *(const bf16x8*)&Qb[((size_t)(q0 + c) << 10) + (g << 3)];
  bf16x8 qf1 = *(const bf16x8*)&Qb[((size_t)(q0 + c) << 10) + 32 + (g << 3)];

  const float SC = 0.125f;  // 1/sqrt(64)
  float m = -1e30f, sum = 0.f;
  f32x4 pacc[4];
#pragma unroll
  for (int dt = 0; dt < 4; ++dt) pacc[dt] = f32x4{0.f, 0.f, 0.f, 0.f};

  stageK(0, 0);
  stageV(0, 0);
  __syncthreads();

#pragma unroll
  for (int cc = 0; cc < 8; ++cc) {
    const int buf = cc & 1;
    if (cc < 7) { stageK(buf ^ 1, cc + 1); stageV(buf ^ 1, cc + 1); }

    // QK^T: 4 tiles of 16 k-rows. st[t]: rows k=16t+4g+r, col q=q0+c.
    f32x4 st[4];
    __builtin_amdgcn_s_setprio(1);
#pragma unroll
    for (int t = 0; t < 4; ++t) {
      const ushort_t* base = &Ks[buf][((t << 4) + c) << 6];
      bf16x8 a0 = *(const bf16x8*)&base[(g ^ c7) << 3];
      bf16x8 a1 = *(const bf16x8*)&base[((4 | g) ^ c7) << 3];
      f32x4 z = {0.f, 0.f, 0.f, 0.f};
      z = __builtin_amdgcn_mfma_f32_16x16x32_bf16(a0, qf0, z, 0, 0, 0);
      z = __builtin_amdgcn_mfma_f32_16x16x32_bf16(a1, qf1, z, 0, 0, 0);
      st[t] = z;
    }
    __builtin_amdgcn_s_setprio(0);

    // online softmax: chunk max (cross-g reduce), rescale running state
    float mx = fmaxf(fmaxf(st[0][0], st[0][1]), fmaxf(st[0][2], st[0][3]));
#pragma unroll
    for (int t = 1; t < 4; ++t)
      mx = fmaxf(mx, fmaxf(fmaxf(st[t][0], st[t][1]), fmaxf(st[t][2], st[t][3])));
    mx = fmaxf(mx, __shfl_xor(mx, 16, 64));
    mx = fmaxf(mx, __shfl_xor(mx, 32, 64));
    const float mn = fmaxf(m, mx);
    const float scale = __expf((m - mn) * SC);
    m = mn;
    float ls = 0.f;
#pragma unroll
    for (int t = 0; t < 4; ++t)
#pragma unroll
      for (int r = 0; r < 4; ++r) {
        float p = __expf((st[t][r] - mn) * SC);
        st[t][r] = p;
        ls += p;
      }
    ls += __shfl_xor(ls, 16, 64);
    ls += __shfl_xor(ls, 32, 64);
    sum = sum * scale + ls;
#pragma unroll
    for (int dt = 0; dt < 4; ++dt)
#pragma unroll
      for (int r = 0; r < 4; ++r) pacc[dt][r] *= scale;

    // PV: 4 K=16 steps; B-frag(k=4g+j, col c) == st[ks] regs, packed in-lane.
#pragma unroll
    for (int ks = 0; ks < 4; ++ks) {
      union { bf16x4 v; u32 wd[2]; } pb;
      pb.wd[0] = cvtpk(st[ks][0], st[ks][1]);
      pb.wd[1] = cvtpk(st[ks][2], st[ks][3]);
      __builtin_amdgcn_s_setprio(1);
#pragma unroll
      for (int dt = 0; dt < 4; ++dt) {
        const int slot = ((ks << 1) | (g >> 1)) ^ c7;
        bf16x4 av = *(const bf16x4*)
            &Vs[buf][(((dt << 4) + c) << 6) + (slot << 3) + ((g & 1) << 2)];
        asm("v_mfma_f32_16x16x16_bf16 %0, %1, %2, %0"
            : "+v"(pacc[dt]) : "v"(av), "v"(pb.v));
      }
      __builtin_amdgcn_s_setprio(0);
    }
    __syncthreads();
  }

  const float inv = 1.0f / sum;
  // ctx h-major: [dir][h][4096][64]; wave writes 16 q-rows x 128B contiguous.
  ushort_t* cb = ctx + ((size_t)dir << 22) + ((size_t)h << 18) +
                 ((size_t)(b * 512 + q0 + c) << 6);
#pragma unroll
  for (int dt = 0; dt < 4; ++dt) {
    union { u16x4 o; u32 wd[2]; } ou;
    ou.wd[0] = cvtpk(pacc[dt][0] * inv, pacc[dt][1] * inv);
    ou.wd[1] = cvtpk(pacc[dt][2] * inv, pacc[dt][3] * inv);
    *(u16x4*)&cb[(dt << 4) + (g << 2)] = ou.o;
  }
}

// ---------------------------------------------------------------------------
// gate = sigmoid(gt + gpart); f = gate*x + (1-gate)*ao; out = LayerNorm(f)
__global__ __launch_bounds__(256) void fuse_ln(
    const float* __restrict__ xt, const float* __restrict__ xc,
    const ushort_t* __restrict__ ao, const ushort_t* __restrict__ gt,
    const ushort_t* __restrict__ gp,
    const float* __restrict__ lng, const float* __restrict__ lnb,
    float* __restrict__ out) {
  const int row = blockIdx.x, dir = row >> 12, r = row & 4095;
  const float* x = (dir ? xc : xt) + ((size_t)r << 10);
  const ushort_t* a = ao + ((size_t)row << 10);
  const ushort_t* g1 = gt + ((size_t)row << 10);
  const ushort_t* g2 = gp + ((size_t)row << 10);
  float* o = out + ((size_t)row << 10);
  const int t = threadIdx.x, w = t >> 6, lane = t & 63;
  f32x4 xv = ((const f32x4*)x)[t];
  u16x4 av = ((const u16x4*)a)[t];
  u16x4 gv = ((const u16x4*)g1)[t];
  u16x4 pv = ((const u16x4*)g2)[t];
  f32x4 f;
  float sm = 0.f, sq = 0.f;
#pragma unroll
  for (int j = 0; j < 4; ++j) {
    float gate = 1.f / (1.f + __expf(-(bf2f(gv[j]) + bf2f(pv[j]))));
    float fv = gate * xv[j] + (1.f - gate) * bf2f(av[j]);
    f[j] = fv; sm += fv; sq += fv * fv;
  }
#pragma unroll
  for (int d = 1; d < 64; d <<= 1) {
    sm += __shfl_xor(sm, d, 64);
    sq += __shfl_xor(sq, d, 64);
  }
  __shared__ float ps[8];
  if (lane == 0) { ps[w] = sm; ps[4 + w] = sq; }
  __syncthreads();
  sm = ps[0] + ps[1] + ps[2] + ps[3];
  sq = ps[4] + ps[5] + ps[6] + ps[7];
  const float mu = sm * (1.f / 1024.f);
  const float var = sq * (1.f / 1024.f) - mu * mu;
  const float rstd = rsqrtf(var + 1e-5f);
  f32x4 lg = ((const f32x4*)lng)[t], lb = ((const f32x4*)lnb)[t];
  f32x4 ov;
#pragma unroll
  for (int j = 0; j < 4; ++j) ov[j] = lg[j] * (f[j] - mu) * rstd + lb[j];
  ((f32x4*)o)[t] = ov;
}

// ---------------------------------------------------------------------------
extern "C" void kernel_launch(void* const* d_in, const int* in_sizes, int n_in,
                              void* d_out, int out_size, void* d_ws, size_t ws_size,
                              hipStream_t stream) {
  (void)in_sizes; (void)n_in; (void)out_size; (void)ws_size;
  const float* title = (const float*)d_in[0];
  const float* content = (const float*)d_in[1];

  char* ws = (char*)d_ws;
  const size_t MB = 1u << 20;
  ushort_t* Xt    = (ushort_t*)(ws + 0 * MB);    // 8 MB bf16 [4096][1024]
  ushort_t* Xc    = (ushort_t*)(ws + 8 * MB);    // 8 MB
  ushort_t* ctx   = (ushort_t*)(ws + 0 * MB);    // 16 MB [2][16][4096][64] (X dead)
  ushort_t* WTall = (ushort_t*)(ws + 16 * MB);   // 16 MB: 8 slots [1024][1024]
  ushort_t* WgT   = (ushort_t*)(ws + 32 * MB);   // 4 MB [1024][2048]
  ushort_t* QKV   = (ushort_t*)(ws + 36 * MB);   // 48 MB: 6 slots of 8 MB
  ushort_t* ao    = (ushort_t*)(ws + 36 * MB);   // 16 MB (QKV slots 0-1, dead post-attn)
  ushort_t* gpart = (ushort_t*)(ws + 52 * MB);   // 16 MB (QKV slots 2-3, dead post-attn)
  ushort_t* gt    = (ushort_t*)(ws + 84 * MB);   // 16 MB bf16 [8192][1024]
  ushort_t* WoBF  = (ushort_t*)(ws + 100 * MB);  // 4 MB: 2 slots [1024][1024]
  ushort_t* WpT   = (ushort_t*)(ws + 104 * MB);  // 4 MB: 2 slots [1024][1024]
  float*    gb2   = (float*)   (ws + 108 * MB);  // 8 KB [2][1024]

  cvt_inputs<<<4096, 256, 0, stream>>>(title, content, Xt, Xc);

  // slots: {t2c_wk,t2c_wv,c2t_wq, t2c_wq,c2t_wk,c2t_wv, t2c_wo,c2t_wo}, gate, Wo x2
  Src11 srcs;
  srcs.p[0] = (const float*)d_in[4];  srcs.p[1] = (const float*)d_in[6];
  srcs.p[2] = (const float*)d_in[10]; srcs.p[3] = (const float*)d_in[2];
  srcs.p[4] = (const float*)d_in[12]; srcs.p[5] = (const float*)d_in[14];
  srcs.p[6] = (const float*)d_in[8];  srcs.p[7] = (const float*)d_in[16];
  srcs.p[8] = (const float*)d_in[18];
  srcs.p[9] = (const float*)d_in[8];  srcs.p[10] = (const float*)d_in[16];
  transpose_cvt<<<dim3(32, 64, 11), 256, 0, stream>>>(srcs, WTall, WgT, WoBF);

  gb2_kernel<<<512, 256, 0, stream>>>((const float*)d_in[9], (const float*)d_in[17],
                                      WgT, gb2);
  gemm_wp<<<dim3(16, 8), 256, 0, stream>>>(WgT, WoBF, WpT);

  Bias8 bq;
  bq.p[0] = (const float*)d_in[5];  bq.p[1] = (const float*)d_in[7];
  bq.p[2] = (const float*)d_in[11]; bq.p[3] = (const float*)d_in[3];
  bq.p[4] = (const float*)d_in[13]; bq.p[5] = (const float*)d_in[15];
  bq.p[6] = (const float*)d_in[19]; bq.p[7] = nullptr;
  gemm_kernel<M_QKVG><<<2048, 256, 0, stream>>>(Xt, Xc, WTall, WgT, WpT, bq, gb2,
                                                QKV, gt);

  attn_kernel<<<2048, 256, 0, stream>>>(QKV, ctx);

  Bias8 bo;
  bo.p[0] = (const float*)d_in[9]; bo.p[1] = (const float*)d_in[17];
  for (int i = 2; i < 8; ++i) bo.p[i] = nullptr;
  gemm_kernel<M_OG><<<1024, 256, 0, stream>>>(ctx, nullptr, WTall, WgT, WpT, bo, gb2,
                                              ao, gpart);

  fuse_ln<<<8192, 256, 0, stream>>>(title, content, ao, gt, gpart,
                                    (const float*)d_in[20], (const float*)d_in[21],
                                    (float*)d_out);
}

// Round 10
// 207.987 us; speedup vs baseline: 1.1778x; 1.0591x over previous
//
#include <hip/hip_runtime.h>
#include <cstdint>
#include <cstddef>

typedef unsigned short ushort_t;
typedef unsigned int u32;
typedef __attribute__((ext_vector_type(8))) short bf16x8;
typedef __attribute__((ext_vector_type(4))) short bf16x4;
typedef __attribute__((ext_vector_type(4))) float f32x4;
typedef __attribute__((ext_vector_type(4))) unsigned short u16x4;

#define DEV static __device__ __forceinline__

DEV ushort_t f2bf(float f) {
  u32 x = __float_as_uint(f);
  x += 0x7fff + ((x >> 16) & 1);
  return (ushort_t)(x >> 16);
}
DEV float bf2f(ushort_t u) { return __uint_as_float(((u32)u) << 16); }

DEV u32 cvtpk(float a, float b) {  // dst.lo = bf16(a), dst.hi = bf16(b)
  u32 r;
  asm("v_cvt_pk_bf16_f32 %0, %1, %2" : "=v"(r) : "v"(a), "v"(b));
  return r;
}

DEV void gload16(const ushort_t* g, ushort_t* l) {
  __builtin_amdgcn_global_load_lds(
      (const __attribute__((address_space(1))) void*)g,
      (__attribute__((address_space(3))) void*)l, 16, 0, 0);
}

// Dims: B=8, S=512, D=1024, H=16, DH=64, M=B*S=4096 per side.

// ---------------------------------------------------------------------------
__global__ __launch_bounds__(256) void cvt_inputs(
    const float* __restrict__ xa, const float* __restrict__ xb,
    ushort_t* __restrict__ oa, ushort_t* __restrict__ ob) {
  int i = blockIdx.x * 256 + threadIdx.x;
  f32x4 va = ((const f32x4*)xa)[i];
  f32x4 vb = ((const f32x4*)xb)[i];
  u16x4 ua, ub;
#pragma unroll
  for (int j = 0; j < 4; ++j) { ua[j] = f2bf(va[j]); ub[j] = f2bf(vb[j]); }
  ((u16x4*)oa)[i] = ua;
  ((u16x4*)ob)[i] = ub;
}

// ---------------------------------------------------------------------------
// z<8: W [K=1024][1024] f32 -> Wt [1024][1024] bf16 into WTall slot z.
// z==8: gate W [2048][1024] -> WgT [1024][2048].
// z==9,10: plain f32->bf16 of Wo into WoBF slot z-9.
struct Src11 { const float* p[11]; };

__global__ __launch_bounds__(256) void transpose_cvt(
    Src11 srcs, ushort_t* __restrict__ WTall, ushort_t* __restrict__ WgT,
    ushort_t* __restrict__ WoBF) {
  const int z = blockIdx.z;
  if (z != 8 && blockIdx.y >= 32) return;
  const float* src = srcs.p[z];
  int tx = threadIdx.x & 31, ty = threadIdx.x >> 5;
  int n0 = blockIdx.x << 5, k0 = blockIdx.y << 5;
  if (z >= 9) {
    ushort_t* dst = WoBF + ((size_t)(z - 9) << 20);
#pragma unroll
    for (int i = 0; i < 4; ++i) {
      size_t off = (size_t)(k0 + ty + i * 8) * 1024 + n0 + tx;
      dst[off] = f2bf(src[off]);
    }
    return;
  }
  const int K = (z == 8) ? 2048 : 1024;
  ushort_t* dst = (z == 8) ? WgT : WTall + ((size_t)z << 20);
  __shared__ float t[32][33];
#pragma unroll
  for (int i = 0; i < 4; ++i)
    t[ty + i * 8][tx] = src[(size_t)(k0 + ty + i * 8) * 1024 + n0 + tx];
  __syncthreads();
#pragma unroll
  for (int i = 0; i < 4; ++i)
    dst[(size_t)(n0 + ty + i * 8) * K + k0 + tx] = f2bf(t[tx][ty + i * 8]);
}

// ---------------------------------------------------------------------------
// gb2[dir][n] = sum_k bo_dir[k] * Wg[1024+k][n]  (= bo @ Wg_bot).
__global__ __launch_bounds__(256) void gb2_kernel(
    const float* __restrict__ bo0, const float* __restrict__ bo1,
    const ushort_t* __restrict__ WgT, float* __restrict__ gb2) {
  const int wgl = blockIdx.x * 4 + (threadIdx.x >> 6);  // 0..2047
  const int lane = threadIdx.x & 63;
  const int dir = wgl >> 10, n = wgl & 1023;
  const float* bo = dir ? bo1 : bo0;
  const ushort_t* wrow = WgT + ((size_t)n << 11) + 1024 + (lane << 4);
  float s = 0.f;
#pragma unroll
  for (int j = 0; j < 16; ++j) s += bo[(lane << 4) + j] * bf2f(wrow[j]);
#pragma unroll
  for (int d = 1; d < 64; d <<= 1) s += __shfl_xor(s, d, 64);
  if (lane == 0) gb2[wgl] = s;
}

// ---------------------------------------------------------------------------
// WpT[g][n][j] = sum_k Wo_g[j][k] * Wg[1024+k][n]   (= (Wo_g @ Wg_bot)^T)
__global__ __launch_bounds__(256, 3) void gemm_wp(
    const ushort_t* __restrict__ WgT, const ushort_t* __restrict__ WoBF,
    ushort_t* __restrict__ WpT) {
  __shared__ ushort_t As[128 * 64];
  __shared__ ushort_t Bs[128 * 64];
  const int tid = threadIdx.x;
  const int w = tid >> 6, lane = tid & 63;
  const int g = lane >> 4, c = lane & 15;
  const int wm = (w >> 1) << 6, wn = (w & 1) << 6;
  const int m0 = blockIdx.x << 7, n0 = blockIdx.y << 7;
  const int group = m0 >> 10;
  const int csw = (lane & 7) ^ (lane >> 3);

  f32x4 acc[4][4];
#pragma unroll
  for (int i = 0; i < 4; ++i)
#pragma unroll
    for (int j = 0; j < 4; ++j) acc[i][j] = f32x4{0.f, 0.f, 0.f, 0.f};

  for (int k0 = 0; k0 < 1024; k0 += 64) {
#pragma unroll
    for (int i = 0; i < 4; ++i) {
      const int chunk = (w << 2) + i;
      const int row = (chunk << 3) + (lane >> 3);
      gload16(WgT + ((size_t)((m0 + row) & 1023) << 11) + 1024 + k0 + (csw << 3),
              &As[(size_t)chunk << 9]);
      gload16(WoBF + ((size_t)group << 20) + ((size_t)(n0 + row) << 10) + k0 + (csw << 3),
              &Bs[(size_t)chunk << 9]);
    }
    __syncthreads();
    const int cg = c & 7;
#pragma unroll
    for (int ks = 0; ks < 2; ++ks) {
      bf16x8 af[4], bfr[4];
#pragma unroll
      for (int mi = 0; mi < 4; ++mi)
        af[mi] = *(const bf16x8*)&As[((wm + mi * 16 + c) << 6) +
                                     ((((ks << 2) | g) ^ cg) << 3)];
#pragma unroll
      for (int ni = 0; ni < 4; ++ni)
        bfr[ni] = *(const bf16x8*)&Bs[((wn + ni * 16 + c) << 6) +
                                      ((((ks << 2) | g) ^ cg) << 3)];
#pragma unroll
      for (int mi = 0; mi < 4; ++mi)
#pragma unroll
        for (int ni = 0; ni < 4; ++ni)
          acc[mi][ni] = __builtin_amdgcn_mfma_f32_16x16x32_bf16(
              af[mi], bfr[ni], acc[mi][ni], 0, 0, 0);
    }
    __syncthreads();
  }
#pragma unroll
  for (int ni = 0; ni < 4; ++ni) {
    const int n = n0 + wn + ni * 16 + c;
#pragma unroll
    for (int mi = 0; mi < 4; ++mi) {
      const int mb = m0 + wm + mi * 16 + (g << 2);
      f32x4 a = acc[mi][ni];
#pragma unroll
      for (int r = 0; r < 4; ++r)
        WpT[((size_t)group << 20) + ((size_t)((mb + r) & 1023) << 10) + n] = f2bf(a[r]);
    }
  }
}

// ---------------------------------------------------------------------------
// 128x128 / BK=64 / 4-wave GEMM — proven engine (single 32KB buffer,
// 16 MFMA/barrier, LDS-staged coalesced epilogue).
// ctx (OG input) is [dir][h][4096][64] (h-major); Q/K slots [4096][1024];
// V slots [b][h][d][s].
enum { M_QKVG = 0, M_OG = 1 };
struct Bias8 { const float* p[8]; };

template <int MODE>
__global__ __launch_bounds__(256, 3) void gemm_kernel(
    const ushort_t* __restrict__ Aa, const ushort_t* __restrict__ Ab,
    const ushort_t* __restrict__ WTall, const ushort_t* __restrict__ WgT,
    const ushort_t* __restrict__ WpT, Bias8 bt, const float* __restrict__ gb2,
    ushort_t* __restrict__ outQ, ushort_t* __restrict__ gt) {
  __shared__ ushort_t smem[16384];  // 32 KB: As | Bs, reused as C-tile
  ushort_t* As = smem;
  ushort_t* Bs = smem + 8192;
  const int tid = threadIdx.x;
  const int w = tid >> 6, lane = tid & 63;
  const int g = lane >> 4, c = lane & 15;
  const int wm = (w >> 1) << 6, wn = (w & 1) << 6;
  const int bid = (int)blockIdx.x;
  const int xcd = bid & 7, idx = bid >> 3;
  const int mt = (xcd << 3) + (idx & 7), nt = idx >> 3;
  const int m0 = mt << 7, n0 = nt << 7;
  const int group = m0 >> 12;
  const int nch = n0 >> 10;
  const int csw = (lane & 7) ^ (lane >> 3);

  const ushort_t* Asrc = (MODE == M_QKVG)
      ? ((group ? Ab : Aa) + ((size_t)(m0 & 4095) << 10))
      : (Aa + ((size_t)group << 22) + ((size_t)(m0 & 4095) << 6));

  const ushort_t* Bb;
  int bstr, bidx = -1;
  if (MODE == M_QKVG) {
    if (nch < 3) {
      bidx = group * 3 + nch;
      Bb = WTall + ((size_t)bidx << 20) + ((size_t)(n0 & 1023) << 10);
      bstr = 1024;
    } else {
      Bb = WgT + ((size_t)(n0 & 1023) << 11);
      bstr = 2048;
    }
  } else {
    if (nch == 0) {
      Bb = WTall + ((size_t)(6 + group) << 20) + ((size_t)n0 << 10);
      bstr = 1024;
    } else {
      Bb = WpT + ((size_t)group << 20) + ((size_t)(n0 & 1023) << 10);
      bstr = 1024;
    }
  }

  f32x4 acc[4][4];
#pragma unroll
  for (int i = 0; i < 4; ++i)
#pragma unroll
    for (int j = 0; j < 4; ++j) acc[i][j] = f32x4{0.f, 0.f, 0.f, 0.f};

  for (int k0 = 0; k0 < 1024; k0 += 64) {
#pragma unroll
    for (int i = 0; i < 4; ++i) {
      const int chunk = (w << 2) + i;
      const int row = (chunk << 3) + (lane >> 3);
      const ushort_t* ap;
      if (MODE == M_QKVG)
        ap = Asrc + ((size_t)row << 10) + k0 + (csw << 3);
      else  // ctx h-major: h = k0>>6, d = csw*8
        ap = Asrc + ((size_t)(k0 >> 6) << 18) + ((size_t)row << 6) + (csw << 3);
      gload16(ap, &As[(size_t)chunk << 9]);
      gload16(Bb + (size_t)row * bstr + k0 + (csw << 3), &Bs[(size_t)chunk << 9]);
    }
    __syncthreads();
    const int cg = c & 7;
#pragma unroll
    for (int ks = 0; ks < 2; ++ks) {
      bf16x8 af[4], bfr[4];
#pragma unroll
      for (int mi = 0; mi < 4; ++mi)
        af[mi] = *(const bf16x8*)&As[((wm + mi * 16 + c) << 6) +
                                     ((((ks << 2) | g) ^ cg) << 3)];
#pragma unroll
      for (int ni = 0; ni < 4; ++ni)
        bfr[ni] = *(const bf16x8*)&Bs[((wn + ni * 16 + c) << 6) +
                                      ((((ks << 2) | g) ^ cg) << 3)];
#pragma unroll
      for (int mi = 0; mi < 4; ++mi)
#pragma unroll
        for (int ni = 0; ni < 4; ++ni)
          acc[mi][ni] = __builtin_amdgcn_mfma_f32_16x16x32_bf16(
              af[mi], bfr[ni], acc[mi][ni], 0, 0, 0);
    }
    __syncthreads();
  }

  // Epilogue. D frag: row(M) = 4*(lane>>4)+reg, col(N) = lane&15.
  const bool vt_path = (MODE == M_QKVG) && (nch < 3) && (bidx == 1 || bidx == 5);
  if (vt_path) {
#pragma unroll
    for (int ni = 0; ni < 4; ++ni) {
      const int nloc = (n0 + wn + ni * 16 + c) & 1023;
      const float bv = bt.p[bidx][nloc];
      const int h = nloc >> 6, d = nloc & 63;
#pragma unroll
      for (int mi = 0; mi < 4; ++mi) {
        const int mrow = (m0 + wm + mi * 16 + (g << 2)) & 4095;
        const int b = mrow >> 9, s = mrow & 511;
        f32x4 a = acc[mi][ni];
        u16x4 o;
#pragma unroll
        for (int r = 0; r < 4; ++r) o[r] = f2bf(a[r] + bv);
        *(u16x4*)&outQ[((size_t)bidx << 22) +
                       (((size_t)((b * 16 + h) * 64 + d)) << 9) + s] = o;
      }
    }
  } else {
    // Stage bf16 C-tile in LDS, then 8 rounds of coalesced bf16x8 row stores.
#pragma unroll
    for (int ni = 0; ni < 4; ++ni) {
      const int col = wn + ni * 16 + c;
      const int nloc = (n0 + col) & 1023;
      float bv;
      if (MODE == M_QKVG)
        bv = (nch < 3) ? bt.p[bidx][nloc]
                       : bt.p[6][nloc] + gb2[(group << 10) + nloc];
      else
        bv = (nch == 0) ? bt.p[group][nloc] : 0.f;
#pragma unroll
      for (int mi = 0; mi < 4; ++mi) {
        const int rowb = wm + mi * 16 + (g << 2);
        f32x4 a = acc[mi][ni];
#pragma unroll
        for (int r = 0; r < 4; ++r)
          smem[((rowb + r) << 7) + col] = f2bf(a[r] + bv);
      }
    }
    __syncthreads();
    const int lr = tid >> 4;          // 0..15
    const int lc = (tid & 15) << 3;   // 0..120, step 8
    ushort_t* obase;
    size_t rbase;
    if (MODE == M_QKVG) {
      if (nch < 3) { obase = outQ + ((size_t)bidx << 22); rbase = (size_t)(m0 & 4095); }
      else         { obase = gt;                          rbase = (size_t)m0; }
    } else {
      if (nch == 0) { obase = outQ; rbase = (size_t)m0; }
      else          { obase = gt;   rbase = (size_t)m0; }
    }
    const int ncol = (n0 & 1023) + lc;
#pragma unroll
    for (int j = 0; j < 8; ++j) {
      const int row = (j << 4) + lr;
      bf16x8 v = *(const bf16x8*)&smem[(row << 7) + lc];
      *(bf16x8*)&obase[((rbase + row) << 10) + ncol] = v;
    }
  }
}

// ---------------------------------------------------------------------------
// Flash-style fused attention, both dirs. 1024 blocks: each handles 128 q-rows
// (wave = 2 independent 16-col q-groups) -> half the blocks, half the K/V L2
// traffic, 2x MFMA per barrier, two independent softmax chains per wave (ILP).
// Q/K slots [4096][1024] natural; V slots [b][h][d][s]. KL row-shift dropped
// (softmax shift-invariant). QK^T = mfma(K,Q) 16x16x32; PV = 16x16x16 (P frag
// == QK^T out frag, zero shuffles). T13 defer-max: skip rescale while
// chunk-max <= m+64 (P bounded by e^8, exact in f32).
__global__ __launch_bounds__(256, 4) void attn_kernel(
    const ushort_t* __restrict__ QKV, ushort_t* __restrict__ ctx) {
  __shared__ ushort_t Ks[2][4096];
  __shared__ ushort_t Vs[2][4096];
  const int tid = threadIdx.x, w = tid >> 6, lane = tid & 63;
  const int g = lane >> 4, c = lane & 15, c7 = c & 7;
  const int bid = (int)blockIdx.x;
  const int wid = (bid & 7) * 128 + (bid >> 3);  // XCD-contiguous, 1024 total
  const int dir = wid >> 9;
  const int bh = (wid >> 2) & 127, qt = wid & 3;
  const int b = bh >> 4, h = bh & 15;
  const int q0 = (qt << 7) + (w << 4);  // group A rows; group B = q0 + 64
  const int qs = dir ? 2 : 3, kslot = dir ? 4 : 0, vslot = dir ? 5 : 1;
  const ushort_t* Qb = QKV + ((size_t)qs << 22) + (((size_t)b << 9) << 10) + (h << 6);
  const ushort_t* Kb = QKV + ((size_t)kslot << 22) + (((size_t)b << 9) << 10) + (h << 6);
  const ushort_t* Vb = QKV + ((size_t)vslot << 22) + ((size_t)bh << 15);  // [64][512]

  auto stageK = [&](int bb, int kc) {
#pragma unroll
    for (int i = 0; i < 2; ++i) {
      int idx = tid + (i << 8);
      int r = idx >> 3, sl = idx & 7;
      int cs = sl ^ (r & 7);
      gload16(Kb + ((size_t)((kc << 6) + r) << 10) + (cs << 3), &Ks[bb][idx << 3]);
    }
  };
  auto stageV = [&](int bb, int vc) {
#pragma unroll
    for (int i = 0; i < 2; ++i) {
      int idx = tid + (i << 8);
      int r = idx >> 3, sl = idx & 7;
      int cs = sl ^ (r & 7);
      gload16(Vb + ((size_t)r << 9) + (vc << 6) + (cs << 3), &Vs[bb][idx << 3]);
    }
  };

  bf16x8 qfA0 = *(const bf16x8*)&Qb[((size_t)(q0 + c) << 10) + (g << 3)];
  bf16x8 qfA1 = *(const bf16x8*)&Qb[((size_t)(q0 + c) << 10) + 32 + (g << 3)];
  bf16x8 qfB0 = *(const bf16x8*)&Qb[((size_t)(q0 + 64 + c) << 10) + (g << 3)];
  bf16x8 qfB1 = *(const bf16x8*)&Qb[((size_t)(q0 + 64 + c) << 10) + 32 + (g << 3)];

  const float SC = 0.125f;  // 1/sqrt(64)
  float mA = -1e30f, sumA = 0.f, mB = -1e30f, sumB = 0.f;
  f32x4 paccA[4], paccB[4];
#pragma unroll
  for (int dt = 0; dt < 4; ++dt) {
    paccA[dt] = f32x4{0.f, 0.f, 0.f, 0.f};
    paccB[dt] = f32x4{0.f, 0.f, 0.f, 0.f};
  }

  stageK(0, 0);
  stageV(0, 0);
  __syncthreads();

#pragma unroll
  for (int cc = 0; cc < 8; ++cc) {
    const int buf = cc & 1;
    if (cc < 7) { stageK(buf ^ 1, cc + 1); stageV(buf ^ 1, cc + 1); }

    // QK^T: 4 tiles of 16 k-rows; K frags shared by both q-groups.
    f32x4 stA[4], stB[4];
    __builtin_amdgcn_s_setprio(1);
#pragma unroll
    for (int t = 0; t < 4; ++t) {
      const ushort_t* base = &Ks[buf][((t << 4) + c) << 6];
      bf16x8 a0 = *(const bf16x8*)&base[(g ^ c7) << 3];
      bf16x8 a1 = *(const bf16x8*)&base[((4 | g) ^ c7) << 3];
      f32x4 zA = {0.f, 0.f, 0.f, 0.f}, zB = {0.f, 0.f, 0.f, 0.f};
      zA = __builtin_amdgcn_mfma_f32_16x16x32_bf16(a0, qfA0, zA, 0, 0, 0);
      zB = __builtin_amdgcn_mfma_f32_16x16x32_bf16(a0, qfB0, zB, 0, 0, 0);
      zA = __builtin_amdgcn_mfma_f32_16x16x32_bf16(a1, qfA1, zA, 0, 0, 0);
      zB = __builtin_amdgcn_mfma_f32_16x16x32_bf16(a1, qfB1, zB, 0, 0, 0);
      stA[t] = zA;
      stB[t] = zB;
    }
    __builtin_amdgcn_s_setprio(0);

    // online softmax, two independent chains (A,B) with defer-max.
    float mxA = fmaxf(fmaxf(stA[0][0], stA[0][1]), fmaxf(stA[0][2], stA[0][3]));
    float mxB = fmaxf(fmaxf(stB[0][0], stB[0][1]), fmaxf(stB[0][2], stB[0][3]));
#pragma unroll
    for (int t = 1; t < 4; ++t) {
      mxA = fmaxf(mxA, fmaxf(fmaxf(stA[t][0], stA[t][1]), fmaxf(stA[t][2], stA[t][3])));
      mxB = fmaxf(mxB, fmaxf(fmaxf(stB[t][0], stB[t][1]), fmaxf(stB[t][2], stB[t][3])));
    }
    mxA = fmaxf(mxA, __shfl_xor(mxA, 16, 64));
    mxB = fmaxf(mxB, __shfl_xor(mxB, 16, 64));
    mxA = fmaxf(mxA, __shfl_xor(mxA, 32, 64));
    mxB = fmaxf(mxB, __shfl_xor(mxB, 32, 64));
    if (!__all(mxA <= mA + 64.f)) {  // 64 pre-scale = 8 post-scale
      const float mn = fmaxf(mA, mxA);
      const float sc = __expf((mA - mn) * SC);
      mA = mn;
      sumA *= sc;
#pragma unroll
      for (int dt = 0; dt < 4; ++dt)
#pragma unroll
        for (int r = 0; r < 4; ++r) paccA[dt][r] *= sc;
    }
    if (!__all(mxB <= mB + 64.f)) {
      const float mn = fmaxf(mB, mxB);
      const float sc = __expf((mB - mn) * SC);
      mB = mn;
      sumB *= sc;
#pragma unroll
      for (int dt = 0; dt < 4; ++dt)
#pragma unroll
        for (int r = 0; r < 4; ++r) paccB[dt][r] *= sc;
    }
    float lsA = 0.f, lsB = 0.f;
#pragma unroll
    for (int t = 0; t < 4; ++t)
#pragma unroll
      for (int r = 0; r < 4; ++r) {
        float pA = __expf((stA[t][r] - mA) * SC);
        float pB = __expf((stB[t][r] - mB) * SC);
        stA[t][r] = pA;
        stB[t][r] = pB;
        lsA += pA;
        lsB += pB;
      }
    lsA += __shfl_xor(lsA, 16, 64);
    lsB += __shfl_xor(lsB, 16, 64);
    lsA += __shfl_xor(lsA, 32, 64);
    lsB += __shfl_xor(lsB, 32, 64);
    sumA += lsA;
    sumB += lsB;

    // PV: 4 K=16 steps; V frag loaded once, feeds both accumulator sets.
#pragma unroll
    for (int ks = 0; ks < 4; ++ks) {
      union { bf16x4 v; u32 wd[2]; } pbA, pbB;
      pbA.wd[0] = cvtpk(stA[ks][0], stA[ks][1]);
      pbA.wd[1] = cvtpk(stA[ks][2], stA[ks][3]);
      pbB.wd[0] = cvtpk(stB[ks][0], stB[ks][1]);
      pbB.wd[1] = cvtpk(stB[ks][2], stB[ks][3]);
      __builtin_amdgcn_s_setprio(1);
#pragma unroll
      for (int dt = 0; dt < 4; ++dt) {
        const int slot = ((ks << 1) | (g >> 1)) ^ c7;
        bf16x4 av = *(const bf16x4*)
            &Vs[buf][(((dt << 4) + c) << 6) + (slot << 3) + ((g & 1) << 2)];
        asm("v_mfma_f32_16x16x16_bf16 %0, %1, %2, %0"
            : "+v"(paccA[dt]) : "v"(av), "v"(pbA.v));
        asm("v_mfma_f32_16x16x16_bf16 %0, %1, %2, %0"
            : "+v"(paccB[dt]) : "v"(av), "v"(pbB.v));
      }
      __builtin_amdgcn_s_setprio(0);
    }
    __syncthreads();
  }

  const float invA = 1.0f / sumA;
  const float invB = 1.0f / sumB;
  // ctx h-major: [dir][h][4096][64]
  ushort_t* cbA = ctx + ((size_t)dir << 22) + ((size_t)h << 18) +
                  ((size_t)(b * 512 + q0 + c) << 6);
  ushort_t* cbB = cbA + ((size_t)64 << 6);
#pragma unroll
  for (int dt = 0; dt < 4; ++dt) {
    union { u16x4 o; u32 wd[2]; } oa, ob;
    oa.wd[0] = cvtpk(paccA[dt][0] * invA, paccA[dt][1] * invA);
    oa.wd[1] = cvtpk(paccA[dt][2] * invA, paccA[dt][3] * invA);
    ob.wd[0] = cvtpk(paccB[dt][0] * invB, paccB[dt][1] * invB);
    ob.wd[1] = cvtpk(paccB[dt][2] * invB, paccB[dt][3] * invB);
    *(u16x4*)&cbA[(dt << 4) + (g << 2)] = oa.o;
    *(u16x4*)&cbB[(dt << 4) + (g << 2)] = ob.o;
  }
}

// ---------------------------------------------------------------------------
// gate = sigmoid(gt + gpart); f = gate*x + (1-gate)*ao; out = LayerNorm(f)
__global__ __launch_bounds__(256) void fuse_ln(
    const float* __restrict__ xt, const float* __restrict__ xc,
    const ushort_t* __restrict__ ao, const ushort_t* __restrict__ gt,
    const ushort_t* __restrict__ gp,
    const float* __restrict__ lng, const float* __restrict__ lnb,
    float* __restrict__ out) {
  const int row = blockIdx.x, dir = row >> 12, r = row & 4095;
  const float* x = (dir ? xc : xt) + ((size_t)r << 10);
  const ushort_t* a = ao + ((size_t)row << 10);
  const ushort_t* g1 = gt + ((size_t)row << 10);
  const ushort_t* g2 = gp + ((size_t)row << 10);
  float* o = out + ((size_t)row << 10);
  const int t = threadIdx.x, w = t >> 6, lane = t & 63;
  f32x4 xv = ((const f32x4*)x)[t];
  u16x4 av = ((const u16x4*)a)[t];
  u16x4 gv = ((const u16x4*)g1)[t];
  u16x4 pv = ((const u16x4*)g2)[t];
  f32x4 f;
  float sm = 0.f, sq = 0.f;
#pragma unroll
  for (int j = 0; j < 4; ++j) {
    float gate = 1.f / (1.f + __expf(-(bf2f(gv[j]) + bf2f(pv[j]))));
    float fv = gate * xv[j] + (1.f - gate) * bf2f(av[j]);
    f[j] = fv; sm += fv; sq += fv * fv;
  }
#pragma unroll
  for (int d = 1; d < 64; d <<= 1) {
    sm += __shfl_xor(sm, d, 64);
    sq += __shfl_xor(sq, d, 64);
  }
  __shared__ float ps[8];
  if (lane == 0) { ps[w] = sm; ps[4 + w] = sq; }
  __syncthreads();
  sm = ps[0] + ps[1] + ps[2] + ps[3];
  sq = ps[4] + ps[5] + ps[6] + ps[7];
  const float mu = sm * (1.f / 1024.f);
  const float var = sq * (1.f / 1024.f) - mu * mu;
  const float rstd = rsqrtf(var + 1e-5f);
  f32x4 lg = ((const f32x4*)lng)[t], lb = ((const f32x4*)lnb)[t];
  f32x4 ov;
#pragma unroll
  for (int j = 0; j < 4; ++j) ov[j] = lg[j] * (f[j] - mu) * rstd + lb[j];
  ((f32x4*)o)[t] = ov;
}

// ---------------------------------------------------------------------------
extern "C" void kernel_launch(void* const* d_in, const int* in_sizes, int n_in,
                              void* d_out, int out_size, void* d_ws, size_t ws_size,
                              hipStream_t stream) {
  (void)in_sizes; (void)n_in; (void)out_size; (void)ws_size;
  const float* title = (const float*)d_in[0];
  const float* content = (const float*)d_in[1];

  char* ws = (char*)d_ws;
  const size_t MB = 1u << 20;
  ushort_t* Xt    = (ushort_t*)(ws + 0 * MB);    // 8 MB bf16 [4096][1024]
  ushort_t* Xc    = (ushort_t*)(ws + 8 * MB);    // 8 MB
  ushort_t* ctx   = (ushort_t*)(ws + 0 * MB);    // 16 MB [2][16][4096][64] (X dead)
  ushort_t* WTall = (ushort_t*)(ws + 16 * MB);   // 16 MB: 8 slots [1024][1024]
  ushort_t* WgT   = (ushort_t*)(ws + 32 * MB);   // 4 MB [1024][2048]
  ushort_t* QKV   = (ushort_t*)(ws + 36 * MB);   // 48 MB: 6 slots of 8 MB
  ushort_t* ao    = (ushort_t*)(ws + 36 * MB);   // 16 MB (QKV slots 0-1, dead post-attn)
  ushort_t* gpart = (ushort_t*)(ws + 52 * MB);   // 16 MB (QKV slots 2-3, dead post-attn)
  ushort_t* gt    = (ushort_t*)(ws + 84 * MB);   // 16 MB bf16 [8192][1024]
  ushort_t* WoBF  = (ushort_t*)(ws + 100 * MB);  // 4 MB: 2 slots [1024][1024]
  ushort_t* WpT   = (ushort_t*)(ws + 104 * MB);  // 4 MB: 2 slots [1024][1024]
  float*    gb2   = (float*)   (ws + 108 * MB);  // 8 KB [2][1024]

  cvt_inputs<<<4096, 256, 0, stream>>>(title, content, Xt, Xc);

  // slots: {t2c_wk,t2c_wv,c2t_wq, t2c_wq,c2t_wk,c2t_wv, t2c_wo,c2t_wo}, gate, Wo x2
  Src11 srcs;
  srcs.p[0] = (const float*)d_in[4];  srcs.p[1] = (const float*)d_in[6];
  srcs.p[2] = (const float*)d_in[10]; srcs.p[3] = (const float*)d_in[2];
  srcs.p[4] = (const float*)d_in[12]; srcs.p[5] = (const float*)d_in[14];
  srcs.p[6] = (const float*)d_in[8];  srcs.p[7] = (const float*)d_in[16];
  srcs.p[8] = (const float*)d_in[18];
  srcs.p[9] = (const float*)d_in[8];  srcs.p[10] = (const float*)d_in[16];
  transpose_cvt<<<dim3(32, 64, 11), 256, 0, stream>>>(srcs, WTall, WgT, WoBF);

  gb2_kernel<<<512, 256, 0, stream>>>((const float*)d_in[9], (const float*)d_in[17],
                                      WgT, gb2);
  gemm_wp<<<dim3(16, 8), 256, 0, stream>>>(WgT, WoBF, WpT);

  Bias8 bq;
  bq.p[0] = (const float*)d_in[5];  bq.p[1] = (const float*)d_in[7];
  bq.p[2] = (const float*)d_in[11]; bq.p[3] = (const float*)d_in[3];
  bq.p[4] = (const float*)d_in[13]; bq.p[5] = (const float*)d_in[15];
  bq.p[6] = (const float*)d_in[19]; bq.p[7] = nullptr;
  gemm_kernel<M_QKVG><<<2048, 256, 0, stream>>>(Xt, Xc, WTall, WgT, WpT, bq, gb2,
                                                QKV, gt);

  attn_kernel<<<1024, 256, 0, stream>>>(QKV, ctx);

  Bias8 bo;
  bo.p[0] = (const float*)d_in[9]; bo.p[1] = (const float*)d_in[17];
  for (int i = 2; i < 8; ++i) bo.p[i] = nullptr;
  gemm_kernel<M_OG><<<1024, 256, 0, stream>>>(ctx, nullptr, WTall, WgT, WpT, bo, gb2,
                                              ao, gpart);

  fuse_ln<<<8192, 256, 0, stream>>>(title, content, ao, gt, gpart,
                                    (const float*)d_in[20], (const float*)d_in[21],
                                    (float*)d_out);
}